// Round 16
// baseline (250.816 us; speedup 1.0000x reference)
//
#include <hip/hip_runtime.h>

// FeatureMagnet r15: r14 base (216.7us) + 64-row-block epilogue fusions:
//  - k_oln64: combine + out-proj + LN1 (one block owns 64 rows; Wo/Pacc
//    traffic identical to split version: 48x128KB == 192x32KB)
//  - k_f2ln64: FFN2 + LN2 -> d_out (same argument, K=1024)
// r13's 4x weight blowup came from 16-row granularity, not fusion per se.
// 13 -> 10 dispatches. LE=LA=2048, C=256, H=8, DH=32, DF=1024, Lq=3072, Lk=4096.

#define LE 2048
#define LA 2048
#define CDIM 256
#define HN 8
#define DH 32
#define DFF 1024
#define NREM 1024
#define LQC 3072
#define LKC 4096
#define KSPLIT 8
#define NIT (LKC / KSPLIT / 64)   // 8 iterations of 64 keys

typedef unsigned short u16;
typedef unsigned int u32;
typedef __attribute__((ext_vector_type(8))) short bf16x8;
typedef __attribute__((ext_vector_type(4))) float f32x4;

__device__ __forceinline__ u32 pk_bf16(float a, float b) {
    u32 ua = (__builtin_bit_cast(u32, a) + 0x8000u) >> 16;
    u32 ub = (__builtin_bit_cast(u32, b) + 0x8000u) >> 16;
    return ua | (ub << 16);
}
__device__ __forceinline__ u16 bf16_1(float a) {
    return (u16)((__builtin_bit_cast(u32, a) + 0x8000u) >> 16);
}
__device__ __forceinline__ float fast_exp2(float x) {
    return __builtin_amdgcn_exp2f(x);  // v_exp_f32: 2^x
}

// ----------------------------------------- hash-join matching (one block) --
__global__ __launch_bounds__(1024) void k_match(const int* __restrict__ pos_ego,
                                                const int* __restrict__ pos_agent,
                                                int* __restrict__ afe,
                                                int* __restrict__ matched,
                                                int* __restrict__ unmatched) {
    __shared__ int keyA[4096], valA[4096], keyE[4096];
    const int t = threadIdx.x;
#pragma unroll
    for (int i = 0; i < 4; ++i) { keyA[t + i * 1024] = -1; keyE[t + i * 1024] = -1; }
    __syncthreads();
#pragma unroll
    for (int i = 0; i < 2; ++i) {
        int a = t + i * 1024;
        int p = pos_agent[a];
        u32 h = ((u32)p * 2654435761u) >> 20;
        while (true) {
            int prev = atomicCAS(&keyA[h], -1, p);
            if (prev == -1) { valA[h] = a; break; }
            h = (h + 1) & 4095;
        }
        int e = t + i * 1024;
        int pe = pos_ego[e];
        u32 he = ((u32)pe * 2654435761u) >> 20;
        while (true) {
            int prev = atomicCAS(&keyE[he], -1, pe);
            if (prev == -1) break;
            he = (he + 1) & 4095;
        }
    }
    __syncthreads();
#pragma unroll
    for (int i = 0; i < 2; ++i) {
        int e = t + i * 1024;
        int p = pos_ego[e];
        u32 h = ((u32)p * 2654435761u) >> 20;
        int idx = 0, fnd = 0;
        while (true) {
            int k = keyA[h];
            if (k == p) { idx = valA[h]; fnd = 1; break; }
            if (k == -1) break;
            h = (h + 1) & 4095;
        }
        afe[e] = idx;
        matched[e] = fnd;
        int a = t + i * 1024;
        int pa_ = pos_agent[a];
        u32 ha = ((u32)pa_ * 2654435761u) >> 20;
        int fnd2 = 0;
        while (true) {
            int k = keyE[ha];
            if (k == pa_) { fnd2 = 1; break; }
            if (k == -1) break;
            ha = (ha + 1) & 4095;
        }
        unmatched[a] = !fnd2;
    }
}

// ----- fused stage2: scan(b0) + build_fused + cvt_weights + kv staging -----
struct WPtrs { const float* p[7]; };
__constant__ __device__ const int woff[8] = {0, 131072, 196608, 262144,
                                             458752, 524288, 786432, 1048576};

__global__ __launch_bounds__(256) void k_stage2(const int* __restrict__ unmatched,
                                                int* __restrict__ remain,
                                                const int* __restrict__ afe,
                                                const float* __restrict__ x_ego,
                                                const float* __restrict__ x_agent,
                                                u16* __restrict__ fused_b,
                                                WPtrs wp, u16* __restrict__ wb,
                                                u16* __restrict__ kv_b) {
    int b = blockIdx.x;
    if (b == 0) {
        __shared__ int s[256];
        int t = threadIdx.x;
        int base_i = t * 8;
        int flags[8];
        int cnt = 0;
#pragma unroll
        for (int j = 0; j < 8; ++j) { flags[j] = unmatched[base_i + j]; cnt += flags[j]; }
        s[t] = cnt;
        __syncthreads();
        for (int off = 1; off < 256; off <<= 1) {
            int v = (t >= off) ? s[t - off] : 0;
            __syncthreads();
            s[t] += v;
            __syncthreads();
        }
        int pos = s[t] - cnt;
#pragma unroll
        for (int j = 0; j < 8; ++j) {
            if (flags[j]) {
                if (pos < NREM) remain[pos] = base_i + j;
                pos++;
            }
        }
    } else if (b <= 512) {
        int t = (b - 1) * 256 + threadIdx.x;  // LE*64
        int e = t >> 6, c8 = t & 63;
        const float* src;
        int col;
        if (c8 < 32) { src = x_ego + (size_t)e * CDIM; col = c8 * 8; }
        else { src = x_agent + (size_t)afe[e] * CDIM; col = (c8 - 32) * 8; }
        float4 f0 = *(const float4*)(src + col);
        float4 f1 = *(const float4*)(src + col + 4);
        uint4 o;
        o.x = pk_bf16(f0.x, f0.y); o.y = pk_bf16(f0.z, f0.w);
        o.z = pk_bf16(f1.x, f1.y); o.w = pk_bf16(f1.z, f1.w);
        *(uint4*)(fused_b + (size_t)e * 512 + c8 * 8) = o;
    } else if (b <= 1024) {
        int g = ((b - 513) * 256 + threadIdx.x) * 8;  // < 1048576
        int s = 0;
#pragma unroll
        for (int i = 1; i < 7; ++i) s += (g >= woff[i]);
        const float* src = wp.p[s] + (g - woff[s]);
        float4 f0 = *(const float4*)(src);
        float4 f1 = *(const float4*)(src + 4);
        uint4 o;
        o.x = pk_bf16(f0.x, f0.y); o.y = pk_bf16(f0.z, f0.w);
        o.z = pk_bf16(f1.x, f1.y); o.w = pk_bf16(f1.z, f1.w);
        *(uint4*)(wb + g) = o;
    } else {
        int t = (b - 1025) * 256 + threadIdx.x;  // LKC*32
        int j = t >> 5, c8 = t & 31;
        const float* src = (j < LE) ? (x_ego + (size_t)j * CDIM)
                                    : (x_agent + (size_t)(j - LE) * CDIM);
        float4 f0 = *(const float4*)(src + c8 * 8);
        float4 f1 = *(const float4*)(src + c8 * 8 + 4);
        uint4 o;
        o.x = pk_bf16(f0.x, f0.y); o.y = pk_bf16(f0.z, f0.w);
        o.z = pk_bf16(f1.x, f1.y); o.w = pk_bf16(f1.z, f1.w);
        *(uint4*)(kv_b + (size_t)j * CDIM + c8 * 8) = o;
    }
}

// --------------------------------------------------------- bf16 MFMA GEMM --
// EPI: 0=f32, 1=bf16
template <int EPI, bool RELU>
__global__ __launch_bounds__(256) void gemm_bf16(const u16* __restrict__ A,
                                                 const u16* __restrict__ B,
                                                 const float* __restrict__ bias,
                                                 void* __restrict__ C,
                                                 int M, int N, int K) {
    const int tid = threadIdx.x;
    const int w = tid >> 6, lane = tid & 63;
    const int quad = lane >> 4, qi = lane & 15;
    const int wm = w >> 1, wn = w & 1;
    const int bm = blockIdx.y * 64, bn = blockIdx.x * 64;

    const u16* pa0 = A + (size_t)(bm + wm * 32 + qi) * K + quad * 8;
    const u16* pa1 = pa0 + (size_t)16 * K;
    const u16* pb0 = B + (size_t)(bn + wn * 32 + qi) * K + quad * 8;
    const u16* pb1 = pb0 + (size_t)16 * K;

    f32x4 acc00 = {0.f, 0.f, 0.f, 0.f}, acc01 = {0.f, 0.f, 0.f, 0.f};
    f32x4 acc10 = {0.f, 0.f, 0.f, 0.f}, acc11 = {0.f, 0.f, 0.f, 0.f};

#pragma unroll 4
    for (int k = 0; k < K; k += 32) {
        bf16x8 a0 = *(const bf16x8*)(pa0 + k);
        bf16x8 a1 = *(const bf16x8*)(pa1 + k);
        bf16x8 b0 = *(const bf16x8*)(pb0 + k);
        bf16x8 b1 = *(const bf16x8*)(pb1 + k);
        acc00 = __builtin_amdgcn_mfma_f32_16x16x32_bf16(a0, b0, acc00, 0, 0, 0);
        acc01 = __builtin_amdgcn_mfma_f32_16x16x32_bf16(a0, b1, acc01, 0, 0, 0);
        acc10 = __builtin_amdgcn_mfma_f32_16x16x32_bf16(a1, b0, acc10, 0, 0, 0);
        acc11 = __builtin_amdgcn_mfma_f32_16x16x32_bf16(a1, b1, acc11, 0, 0, 0);
    }

#pragma unroll
    for (int i = 0; i < 2; ++i) {
#pragma unroll
        for (int j = 0; j < 2; ++j) {
            f32x4 acc = (i == 0) ? (j == 0 ? acc00 : acc01) : (j == 0 ? acc10 : acc11);
            int n = bn + wn * 32 + j * 16 + qi;
            int mbase = bm + wm * 32 + i * 16 + quad * 4;
            float bs = bias[n];
            float v[4];
#pragma unroll
            for (int r = 0; r < 4; ++r) {
                float x = acc[r] + bs;
                if (RELU) x = fmaxf(x, 0.f);
                v[r] = x;
            }
            if (EPI == 0) {
                float* Cf = (float*)C;
#pragma unroll
                for (int r = 0; r < 4; ++r) Cf[(size_t)(mbase + r) * N + n] = v[r];
            } else {
                u16* Cb = (u16*)C;
#pragma unroll
                for (int r = 0; r < 4; ++r) Cb[(size_t)(mbase + r) * N + n] = bf16_1(v[r]);
            }
        }
    }
}

// ------- MLP3 + finalize: qbuf = select(matched, mlp, x_ego) + gather ------
__global__ __launch_bounds__(256) void k_mlp3f(const u16* __restrict__ h2_b,
                                               const u16* __restrict__ Wf3_b,
                                               const float* __restrict__ bf3,
                                               const int* __restrict__ matched,
                                               const int* __restrict__ remain,
                                               const float* __restrict__ x_ego,
                                               const float* __restrict__ x_agent,
                                               float* __restrict__ qbuf,
                                               u16* __restrict__ qbuf_b) {
    const int tid = threadIdx.x;
    const int bn = blockIdx.x * 64, bm = blockIdx.y * 64;
    if (bm >= LE) {  // gather rows LE..LQC
        int row = bm + (tid >> 2);
        int col = bn + (tid & 3) * 16;
        int idx = remain[row - LE];
        idx = min(max(idx, 0), LA - 1);
        const float* src = x_agent + (size_t)idx * CDIM + col;
        float* dq = qbuf + (size_t)row * CDIM + col;
        u16* db = qbuf_b + (size_t)row * CDIM + col;
#pragma unroll
        for (int i = 0; i < 4; ++i) {
            float4 v = *(const float4*)(src + i * 4);
            *(float4*)(dq + i * 4) = v;
            *(uint2*)(db + i * 4) = make_uint2(pk_bf16(v.x, v.y), pk_bf16(v.z, v.w));
        }
        return;
    }
    const int w = tid >> 6, lane = tid & 63;
    const int quad = lane >> 4, qi = lane & 15;
    const int wm = w >> 1, wn = w & 1;
    const u16* pa0 = h2_b + (size_t)(bm + wm * 32 + qi) * 256 + quad * 8;
    const u16* pa1 = pa0 + (size_t)16 * 256;
    const u16* pb0 = Wf3_b + (size_t)(bn + wn * 32 + qi) * 256 + quad * 8;
    const u16* pb1 = pb0 + (size_t)16 * 256;
    f32x4 a00 = {0, 0, 0, 0}, a01 = {0, 0, 0, 0}, a10 = {0, 0, 0, 0}, a11 = {0, 0, 0, 0};
#pragma unroll 4
    for (int k = 0; k < 256; k += 32) {
        bf16x8 x0 = *(const bf16x8*)(pa0 + k);
        bf16x8 x1 = *(const bf16x8*)(pa1 + k);
        bf16x8 y0 = *(const bf16x8*)(pb0 + k);
        bf16x8 y1 = *(const bf16x8*)(pb1 + k);
        a00 = __builtin_amdgcn_mfma_f32_16x16x32_bf16(x0, y0, a00, 0, 0, 0);
        a01 = __builtin_amdgcn_mfma_f32_16x16x32_bf16(x0, y1, a01, 0, 0, 0);
        a10 = __builtin_amdgcn_mfma_f32_16x16x32_bf16(x1, y0, a10, 0, 0, 0);
        a11 = __builtin_amdgcn_mfma_f32_16x16x32_bf16(x1, y1, a11, 0, 0, 0);
    }
#pragma unroll
    for (int i = 0; i < 2; ++i)
#pragma unroll
        for (int jj = 0; jj < 2; ++jj) {
            f32x4 acc = (i == 0) ? (jj == 0 ? a00 : a01) : (jj == 0 ? a10 : a11);
            int n = bn + wn * 32 + jj * 16 + qi;
            int mb = bm + wm * 32 + i * 16 + quad * 4;
            float bs = bf3[n];
#pragma unroll
            for (int r = 0; r < 4; ++r) {
                int row = mb + r;
                float v = acc[r] + bs;
                if (!matched[row]) v = x_ego[(size_t)row * CDIM + n];
                qbuf[(size_t)row * CDIM + n] = v;
                qbuf_b[(size_t)row * CDIM + n] = bf16_1(v);
            }
        }
}

// --------------------------- fused QKV projection (one dispatch) -----------
__global__ __launch_bounds__(256) void k_qkv(const u16* __restrict__ qbuf_b,
                                             const u16* __restrict__ kv_b,
                                             const u16* __restrict__ Wq,
                                             const u16* __restrict__ Wkv,
                                             const float* __restrict__ bqkv,
                                             u16* __restrict__ qb,
                                             u16* __restrict__ kbp,
                                             u16* __restrict__ vtb,
                                             float qscale) {
    int b = blockIdx.x;
    const u16 *A, *B;
    const float* bias;
    int bm, bn, mode;
    if (b < 192) {
        A = qbuf_b; B = Wq; bias = bqkv;
        bm = (b >> 2) * 64; bn = (b & 3) * 64; mode = 0;
    } else {
        int c = b - 192;
        A = kv_b; B = Wkv; bias = bqkv + 256;
        bm = (c >> 3) * 64; bn = (c & 7) * 64; mode = 1;
    }
    const int tid = threadIdx.x;
    const int w = tid >> 6, lane = tid & 63;
    const int quad = lane >> 4, qi = lane & 15;
    const int wm = w >> 1, wn = w & 1;
    const int K = 256;

    const u16* pa0 = A + (size_t)(bm + wm * 32 + qi) * K + quad * 8;
    const u16* pa1 = pa0 + (size_t)16 * K;
    const u16* pb0 = B + (size_t)(bn + wn * 32 + qi) * K + quad * 8;
    const u16* pb1 = pb0 + (size_t)16 * K;

    f32x4 acc00 = {0.f, 0.f, 0.f, 0.f}, acc01 = {0.f, 0.f, 0.f, 0.f};
    f32x4 acc10 = {0.f, 0.f, 0.f, 0.f}, acc11 = {0.f, 0.f, 0.f, 0.f};
#pragma unroll 4
    for (int k = 0; k < 256; k += 32) {
        bf16x8 a0 = *(const bf16x8*)(pa0 + k);
        bf16x8 a1 = *(const bf16x8*)(pa1 + k);
        bf16x8 b0 = *(const bf16x8*)(pb0 + k);
        bf16x8 b1 = *(const bf16x8*)(pb1 + k);
        acc00 = __builtin_amdgcn_mfma_f32_16x16x32_bf16(a0, b0, acc00, 0, 0, 0);
        acc01 = __builtin_amdgcn_mfma_f32_16x16x32_bf16(a0, b1, acc01, 0, 0, 0);
        acc10 = __builtin_amdgcn_mfma_f32_16x16x32_bf16(a1, b0, acc10, 0, 0, 0);
        acc11 = __builtin_amdgcn_mfma_f32_16x16x32_bf16(a1, b1, acc11, 0, 0, 0);
    }
#pragma unroll
    for (int i = 0; i < 2; ++i) {
#pragma unroll
        for (int j = 0; j < 2; ++j) {
            f32x4 acc = (i == 0) ? (j == 0 ? acc00 : acc01) : (j == 0 ? acc10 : acc11);
            int n = bn + wn * 32 + j * 16 + qi;
            int mbase = bm + wm * 32 + i * 16 + quad * 4;
            float bs = bias[n];
            float v[4];
#pragma unroll
            for (int r = 0; r < 4; ++r) v[r] = acc[r] + bs;
            if (mode == 0) {
#pragma unroll
                for (int r = 0; r < 4; ++r)
                    qb[(size_t)(mbase + r) * 256 + n] = bf16_1(v[r] * qscale);
            } else if (n < 256) {
#pragma unroll
                for (int r = 0; r < 4; ++r)
                    kbp[(size_t)(mbase + r) * 256 + n] = bf16_1(v[r]);
            } else {
                ushort4 o4;
                o4.x = bf16_1(v[0]); o4.y = bf16_1(v[1]);
                o4.z = bf16_1(v[2]); o4.w = bf16_1(v[3]);
                *(ushort4*)(vtb + (size_t)(n - 256) * LKC + mbase) = o4;
            }
        }
    }
}

// --------------------------- MFMA attention, LDS-staged K/V tiles ----------
__global__ __launch_bounds__(256) void attn_mfma(const u16* __restrict__ qb,
                                                 const u16* __restrict__ kb,
                                                 const u16* __restrict__ vtb,
                                                 float* __restrict__ Pl,
                                                 float* __restrict__ Pacc) {
    __shared__ u16 Kt[2][64 * 32];
    __shared__ u16 Vt[2][32 * 64];
    __shared__ u16 plds[4][16 * 64];
    const int tid = threadIdx.x;
    const int w = tid >> 6, lane = tid & 63;
    const int quad = lane >> 4, qi = lane & 15;
    const int h = blockIdx.y, ks = blockIdx.z;
    const int q0 = blockIdx.x * 64 + w * 16;

    bf16x8 qf = *(const bf16x8*)(qb + (size_t)(q0 + qi) * CDIM + h * DH + quad * 8);

    f32x4 O0 = {0.f, 0.f, 0.f, 0.f}, O1 = {0.f, 0.f, 0.f, 0.f};
    float lsum = 0.f;

    const int krow = w * 16 + (lane >> 2), kcp = lane & 3;
    const int kc = kcp ^ (krow & 3);
    const u16* kg0 = kb + (size_t)krow * CDIM + h * DH + kc * 8;
    const int kdst = krow * 32 + kcp * 8;
    const int vd = w * 8 + (lane >> 3), vcp = lane & 7;
    const int vc = vcp ^ (vd & 7);
    const u16* vg0 = vtb + (size_t)(h * DH + vd) * LKC + vc * 8;
    const int vdst = vd * 64 + vcp * 8;

    const int ka0 = qi * 32 + ((quad ^ (qi & 3)) << 3);
    const int v00o = qi * 64 + ((quad ^ (qi & 7)) << 3);
    const int v01o = qi * 64 + (((quad + 4) ^ (qi & 7)) << 3);
    const int swz = (qi & 7);
    const int rd0 = qi * 64 + ((quad ^ swz) << 3);
    const int rd1 = qi * 64 + (((4 + quad) ^ swz) << 3);
    const int half = (quad & 1) << 2;

    int kt = ks * (LKC / KSPLIT);
    {
        bf16x8 kr = *(const bf16x8*)(kg0 + (size_t)kt * CDIM);
        bf16x8 vr = *(const bf16x8*)(vg0 + kt);
        *(bf16x8*)&Kt[0][kdst] = kr;
        *(bf16x8*)&Vt[0][vdst] = vr;
    }
    int buf = 0;
    for (int it = 0; it < NIT; ++it, kt += 64) {
        __syncthreads();
        bf16x8 knext, vnext;
        const bool more = (it + 1 < NIT);
        if (more) {
            knext = *(const bf16x8*)(kg0 + (size_t)(kt + 64) * CDIM);
            vnext = *(const bf16x8*)(vg0 + kt + 64);
        }

        bf16x8 a0 = *(const bf16x8*)&Kt[buf][ka0];
        bf16x8 a1 = *(const bf16x8*)&Kt[buf][ka0 + 16 * 32];
        bf16x8 a2 = *(const bf16x8*)&Kt[buf][ka0 + 32 * 32];
        bf16x8 a3 = *(const bf16x8*)&Kt[buf][ka0 + 48 * 32];
        f32x4 z = {0.f, 0.f, 0.f, 0.f};
        f32x4 s0 = __builtin_amdgcn_mfma_f32_16x16x32_bf16(a0, qf, z, 0, 0, 0);
        f32x4 s1 = __builtin_amdgcn_mfma_f32_16x16x32_bf16(a1, qf, z, 0, 0, 0);
        f32x4 s2 = __builtin_amdgcn_mfma_f32_16x16x32_bf16(a2, qf, z, 0, 0, 0);
        f32x4 s3 = __builtin_amdgcn_mfma_f32_16x16x32_bf16(a3, qf, z, 0, 0, 0);

        float p0[4], p1[4], p2[4], p3[4];
#pragma unroll
        for (int r = 0; r < 4; ++r) {
            p0[r] = fast_exp2(s0[r]); p1[r] = fast_exp2(s1[r]);
            p2[r] = fast_exp2(s2[r]); p3[r] = fast_exp2(s3[r]);
            lsum += p0[r] + p1[r] + p2[r] + p3[r];
        }

        u16* pb = &plds[w][0];
#pragma unroll
        for (int t2 = 0; t2 < 4; ++t2) {
            int jg = t2 * 2 + (quad >> 1);
            int off = qi * 64 + ((jg ^ swz) << 3) + half;
            uint2 pw;
            float* pp = (t2 == 0) ? p0 : (t2 == 1) ? p1 : (t2 == 2) ? p2 : p3;
            pw.x = pk_bf16(pp[0], pp[1]);
            pw.y = pk_bf16(pp[2], pp[3]);
            *(uint2*)&pb[off] = pw;
        }
        bf16x8 pa0 = *(bf16x8*)&pb[rd0];
        bf16x8 pa1 = *(bf16x8*)&pb[rd1];

        bf16x8 v00 = *(const bf16x8*)&Vt[buf][v00o];
        bf16x8 v01 = *(const bf16x8*)&Vt[buf][v01o];
        bf16x8 v10 = *(const bf16x8*)&Vt[buf][v00o + 16 * 64];
        bf16x8 v11 = *(const bf16x8*)&Vt[buf][v01o + 16 * 64];
        O0 = __builtin_amdgcn_mfma_f32_16x16x32_bf16(pa0, v00, O0, 0, 0, 0);
        O0 = __builtin_amdgcn_mfma_f32_16x16x32_bf16(pa1, v01, O0, 0, 0, 0);
        O1 = __builtin_amdgcn_mfma_f32_16x16x32_bf16(pa0, v10, O1, 0, 0, 0);
        O1 = __builtin_amdgcn_mfma_f32_16x16x32_bf16(pa1, v11, O1, 0, 0, 0);

        if (more) {
            *(bf16x8*)&Kt[buf ^ 1][kdst] = knext;
            *(bf16x8*)&Vt[buf ^ 1][vdst] = vnext;
        }
        buf ^= 1;
    }

    lsum += __shfl_xor(lsum, 16, 64);
    lsum += __shfl_xor(lsum, 32, 64);

    int pbase = (h * KSPLIT + ks) * LQC + q0;
    if (quad == 0) Pl[pbase + qi] = lsum;
#pragma unroll
    for (int r = 0; r < 4; ++r) {
        int q = quad * 4 + r;
        float* pa = Pacc + (size_t)(pbase + q) * 32;
        pa[qi] = O0[r];
        pa[16 + qi] = O1[r];
    }
}

// ---------- fused combine + out-proj + LN1 (64-row blocks, grid 48) --------
// Weight traffic identical to the tiled version (each 64-row stripe needs all
// of Wo either way). A-tile in LDS (32KB, XOR-swizzled); out f32 in same LDS
// union (64KB); per-wave LN over 16 rows.
__global__ __launch_bounds__(256) void k_oln64(const float* __restrict__ Pl,
                                               const float* __restrict__ Pacc,
                                               const u16* __restrict__ Wo_b,
                                               const float* __restrict__ bo,
                                               const float* __restrict__ qbuf,
                                               const float* __restrict__ g1,
                                               const float* __restrict__ be1,
                                               float* __restrict__ yq,
                                               u16* __restrict__ yq_b) {
    __shared__ __align__(16) float smem[16384];  // 64KB union
    u16* A = (u16*)smem;                         // phase A/B: 64x256 bf16 (32KB)
    const int tid = threadIdx.x;
    const int r0 = blockIdx.x * 64;
    {  // phase A: combine 8 flash partials -> normalized bf16 A
        int row = tid >> 2, t4 = tid & 3;
        int rowg = r0 + row;
#pragma unroll
        for (int hh = 0; hh < 2; ++hh) {
            int h = t4 * 2 + hh;
            float L = 0.f;
            float acc[32] = {};
#pragma unroll
            for (int ck = 0; ck < KSPLIT; ++ck) {
                size_t pidx = (size_t)(h * KSPLIT + ck) * LQC + rowg;
                L += Pl[pidx];
                const float* pa = Pacc + pidx * 32;
#pragma unroll
                for (int i = 0; i < 8; ++i) {
                    float4 v = *(const float4*)(pa + i * 4);
                    acc[i * 4 + 0] += v.x; acc[i * 4 + 1] += v.y;
                    acc[i * 4 + 2] += v.z; acc[i * 4 + 3] += v.w;
                }
            }
            float inv = 1.f / L;
#pragma unroll
            for (int cc = 0; cc < 4; ++cc) {
                int chunk = h * 4 + cc;
                uint4 o;
                o.x = pk_bf16(acc[cc * 8 + 0] * inv, acc[cc * 8 + 1] * inv);
                o.y = pk_bf16(acc[cc * 8 + 2] * inv, acc[cc * 8 + 3] * inv);
                o.z = pk_bf16(acc[cc * 8 + 4] * inv, acc[cc * 8 + 5] * inv);
                o.w = pk_bf16(acc[cc * 8 + 6] * inv, acc[cc * 8 + 7] * inv);
                *(uint4*)&A[row * 256 + ((chunk ^ (row & 7)) << 3)] = o;
            }
        }
    }
    __syncthreads();
    // phase B: 64x64 GEMM per wave (wave w -> cols w*64..), K=256
    const int w = tid >> 6, lane = tid & 63;
    const int quad = lane >> 4, qi = lane & 15;
    f32x4 acc[4][4];
#pragma unroll
    for (int i = 0; i < 4; ++i)
#pragma unroll
        for (int j = 0; j < 4; ++j) acc[i][j] = (f32x4){0.f, 0.f, 0.f, 0.f};
    const u16* pb = Wo_b + (size_t)(w * 64 + qi) * 256 + quad * 8;
#pragma unroll
    for (int ks = 0; ks < 8; ++ks) {
        bf16x8 af[4];
#pragma unroll
        for (int i = 0; i < 4; ++i) {
            int row = i * 16 + qi;
            int chunk = ks * 4 + quad;
            af[i] = *(const bf16x8*)&A[row * 256 + ((chunk ^ (row & 7)) << 3)];
        }
#pragma unroll
        for (int j = 0; j < 4; ++j) {
            bf16x8 bf = *(const bf16x8*)(pb + (size_t)j * 16 * 256 + ks * 32);
#pragma unroll
            for (int i = 0; i < 4; ++i)
                acc[i][j] = __builtin_amdgcn_mfma_f32_16x16x32_bf16(af[i], bf, acc[i][j],
                                                                    0, 0, 0);
        }
    }
    __syncthreads();  // done reading A; reuse LDS as f32 out
#pragma unroll
    for (int i = 0; i < 4; ++i)
#pragma unroll
        for (int j = 0; j < 4; ++j) {
            int col = w * 64 + j * 16 + qi;
            float bs = bo[col];
#pragma unroll
            for (int r = 0; r < 4; ++r)
                smem[(i * 16 + quad * 4 + r) * 256 + col] = acc[i][j][r] + bs;
        }
    __syncthreads();
    // phase C: LN1 with residual, wave w -> rows w*16..w*16+16
#pragma unroll 4
    for (int rr = 0; rr < 16; ++rr) {
        int row = w * 16 + rr;
        int rowg = r0 + row;
        float4 rv = *(const float4*)(qbuf + (size_t)rowg * CDIM + lane * 4);
        const float* orow = &smem[row * 256 + lane * 4];
        float v[4] = {orow[0] + rv.x, orow[1] + rv.y, orow[2] + rv.z, orow[3] + rv.w};
        float s = v[0] + v[1] + v[2] + v[3];
        float sq = v[0] * v[0] + v[1] * v[1] + v[2] * v[2] + v[3] * v[3];
#pragma unroll
        for (int off = 32; off >= 1; off >>= 1) {
            s += __shfl_xor(s, off, 64);
            sq += __shfl_xor(sq, off, 64);
        }
        float mean = s * (1.f / 256.f);
        float var = sq * (1.f / 256.f) - mean * mean;
        float rstd = rsqrtf(var + 1e-5f);
        float4 gv = *(const float4*)(g1 + lane * 4);
        float4 bv = *(const float4*)(be1 + lane * 4);
        float o0 = (v[0] - mean) * rstd * gv.x + bv.x;
        float o1 = (v[1] - mean) * rstd * gv.y + bv.y;
        float o2 = (v[2] - mean) * rstd * gv.z + bv.z;
        float o3 = (v[3] - mean) * rstd * gv.w + bv.w;
        *(float4*)(yq + (size_t)rowg * CDIM + lane * 4) = make_float4(o0, o1, o2, o3);
        *(uint2*)(yq_b + (size_t)rowg * CDIM + lane * 4) =
            make_uint2(pk_bf16(o0, o1), pk_bf16(o2, o3));
    }
}

// ------------- fused FFN2 + LN2 -> d_out (64-row blocks, grid 48) ----------
__global__ __launch_bounds__(256) void k_f2ln64(const u16* __restrict__ ff1_b,
                                                const u16* __restrict__ W2_b,
                                                const float* __restrict__ b2,
                                                const float* __restrict__ yq,
                                                const float* __restrict__ g2,
                                                const float* __restrict__ be2,
                                                float* __restrict__ out) {
    __shared__ __align__(16) float smem[16384];  // 64KB f32 out
    const int tid = threadIdx.x;
    const int r0 = blockIdx.x * 64;
    const int w = tid >> 6, lane = tid & 63;
    const int quad = lane >> 4, qi = lane & 15;
    f32x4 acc[4][4];
#pragma unroll
    for (int i = 0; i < 4; ++i)
#pragma unroll
        for (int j = 0; j < 4; ++j) acc[i][j] = (f32x4){0.f, 0.f, 0.f, 0.f};
    const u16* pa = ff1_b + (size_t)r0 * DFF + quad * 8;
    const u16* pb = W2_b + (size_t)(w * 64 + qi) * DFF + quad * 8;
#pragma unroll 2
    for (int ks = 0; ks < 32; ++ks) {
        bf16x8 af[4];
#pragma unroll
        for (int i = 0; i < 4; ++i)
            af[i] = *(const bf16x8*)(pa + (size_t)(i * 16 + qi) * DFF + ks * 32);
#pragma unroll
        for (int j = 0; j < 4; ++j) {
            bf16x8 bf = *(const bf16x8*)(pb + (size_t)j * 16 * DFF + ks * 32);
#pragma unroll
            for (int i = 0; i < 4; ++i)
                acc[i][j] = __builtin_amdgcn_mfma_f32_16x16x32_bf16(af[i], bf, acc[i][j],
                                                                    0, 0, 0);
        }
    }
#pragma unroll
    for (int i = 0; i < 4; ++i)
#pragma unroll
        for (int j = 0; j < 4; ++j) {
            int col = w * 64 + j * 16 + qi;
            float bs = b2[col];
#pragma unroll
            for (int r = 0; r < 4; ++r)
                smem[(i * 16 + quad * 4 + r) * 256 + col] = acc[i][j][r] + bs;
        }
    __syncthreads();
#pragma unroll 4
    for (int rr = 0; rr < 16; ++rr) {
        int row = w * 16 + rr;
        int rowg = r0 + row;
        float4 rv = *(const float4*)(yq + (size_t)rowg * CDIM + lane * 4);
        const float* orow = &smem[row * 256 + lane * 4];
        float v[4] = {orow[0] + rv.x, orow[1] + rv.y, orow[2] + rv.z, orow[3] + rv.w};
        float s = v[0] + v[1] + v[2] + v[3];
        float sq = v[0] * v[0] + v[1] * v[1] + v[2] * v[2] + v[3] * v[3];
#pragma unroll
        for (int off = 32; off >= 1; off >>= 1) {
            s += __shfl_xor(s, off, 64);
            sq += __shfl_xor(sq, off, 64);
        }
        float mean = s * (1.f / 256.f);
        float var = sq * (1.f / 256.f) - mean * mean;
        float rstd = rsqrtf(var + 1e-5f);
        float4 gv = *(const float4*)(g2 + lane * 4);
        float4 bv = *(const float4*)(be2 + lane * 4);
        float4 o = make_float4((v[0] - mean) * rstd * gv.x + bv.x,
                               (v[1] - mean) * rstd * gv.y + bv.y,
                               (v[2] - mean) * rstd * gv.z + bv.z,
                               (v[3] - mean) * rstd * gv.w + bv.w);
        *(float4*)(out + (size_t)rowg * CDIM + lane * 4) = o;
    }
}

// ------------------------------------------------------------------ launch --
extern "C" void kernel_launch(void* const* d_in, const int* in_sizes, int n_in,
                              void* d_out, int out_size, void* d_ws, size_t ws_size,
                              hipStream_t stream) {
    const float* x_ego = (const float*)d_in[0];
    const float* x_agent = (const float*)d_in[1];
    const float* Wf1 = (const float*)d_in[2];
    const float* bf1 = (const float*)d_in[3];
    const float* Wf2 = (const float*)d_in[4];
    const float* bf2 = (const float*)d_in[5];
    const float* Wf3 = (const float*)d_in[6];
    const float* bf3 = (const float*)d_in[7];
    const float* Wqkv = (const float*)d_in[8];
    const float* bqkv = (const float*)d_in[9];
    const float* Wo = (const float*)d_in[10];
    const float* bo = (const float*)d_in[11];
    const float* W1 = (const float*)d_in[12];
    const float* b1 = (const float*)d_in[13];
    const float* W2 = (const float*)d_in[14];
    const float* b2 = (const float*)d_in[15];
    const float* g1 = (const float*)d_in[16];
    const float* be1 = (const float*)d_in[17];
    const float* g2 = (const float*)d_in[18];
    const float* be2 = (const float*)d_in[19];
    const int* pos_ego = (const int*)d_in[20];
    const int* pos_agent = (const int*)d_in[21];

    float* ws = (float*)d_ws;
    size_t o = 0;
    float* qbuf = ws + o; o += 786432;
    float* yq = ws + o; o += 786432;
    float* Pl = ws + o; o += HN * KSPLIT * LQC;                 // 196608
    float* Pacc = ws + o; o += (size_t)HN * KSPLIT * LQC * 32;  // 6291456
    u16* wb = (u16*)(ws + o); o += 524288;        // 1,048,576 u16
    u16* fused_b = (u16*)(ws + o); o += 524288;   // LE*512
    u16* h1_b = (u16*)(ws + o); o += 262144;      // LE*256
    u16* h2_b = (u16*)(ws + o); o += 262144;
    u16* qbuf_b = (u16*)(ws + o); o += 393216;    // LQC*256
    u16* kv_b = (u16*)(ws + o); o += 524288;      // LKC*256
    u16* qb = (u16*)(ws + o); o += 393216;
    u16* kb = (u16*)(ws + o); o += 524288;
    u16* vtb = (u16*)(ws + o); o += 524288;
    u16* ff1_b = (u16*)(ws + o); o += 1572864;    // LQC*1024
    u16* yq_b = (u16*)(ws + o); o += 393216;
    int* afe = (int*)(ws + o);
    int* matched = afe + LE;
    int* unmatched = matched + LE;
    int* remain = unmatched + LA;

    const u16* Wf1_b = wb + 0;
    const u16* Wf2_b = wb + 131072;
    const u16* Wf3_b = wb + 196608;
    const u16* Wq_b = wb + 262144;
    const u16* Wkv_b = wb + 327680;
    const u16* Wo_b = wb + 458752;
    const u16* W1_b = wb + 524288;
    const u16* W2_b = wb + 786432;

    // 1. matching (LDS hash join)
    k_match<<<1, 1024, 0, stream>>>(pos_ego, pos_agent, afe, matched, unmatched);
    WPtrs wp;
    wp.p[0] = Wf1; wp.p[1] = Wf2; wp.p[2] = Wf3; wp.p[3] = Wqkv;
    wp.p[4] = Wo; wp.p[5] = W1; wp.p[6] = W2;
    // 2. stage2: scan + build_fused + weight cvt + kv staging
    k_stage2<<<1537, 256, 0, stream>>>(unmatched, remain, afe, x_ego, x_agent,
                                       fused_b, wp, wb, kv_b);

    const float qscale = 0.17677669529663687f * 1.4426950408889634f;

    // 3-5. fusion MLP (finalize folded into MLP3)
    gemm_bf16<1, true><<<dim3(4, 32), 256, 0, stream>>>(fused_b, Wf1_b, bf1, h1_b,
                                                        LE, 256, 512);
    gemm_bf16<1, true><<<dim3(4, 32), 256, 0, stream>>>(h1_b, Wf2_b, bf2, h2_b,
                                                        LE, 256, 256);
    k_mlp3f<<<dim3(4, 48), 256, 0, stream>>>(h2_b, Wf3_b, bf3, matched, remain,
                                             x_ego, x_agent, qbuf, qbuf_b);

    // 6. fused QKV projections
    k_qkv<<<704, 256, 0, stream>>>(qbuf_b, kv_b, Wq_b, Wkv_b, bqkv, qb, kb, vtb, qscale);

    // 7. attention (KSPLIT=8)
    attn_mfma<<<dim3(LQC / 64, HN, KSPLIT), 256, 0, stream>>>(qb, kb, vtb, Pl, Pacc);

    // 8. combine + out-proj + LN1 (64-row blocks)
    k_oln64<<<LQC / 64, 256, 0, stream>>>(Pl, Pacc, Wo_b, bo, qbuf, g1, be1, yq, yq_b);

    // 9. FFN1
    gemm_bf16<1, true><<<dim3(16, 48), 256, 0, stream>>>(yq_b, W1_b, b1, ff1_b,
                                                         LQC, DFF, 256);
    // 10. FFN2 + LN2 -> out (64-row blocks)
    k_f2ln64<<<LQC / 64, 256, 0, stream>>>(ff1_b, W2_b, b2, yq, g2, be2, (float*)d_out);
}

// Round 17
// 219.607 us; speedup vs baseline: 1.1421x; 1.1421x over previous
//
#include <hip/hip_runtime.h>

// FeatureMagnet r16: r14/r15 champion (216.7us) + build_fused folded into
// MLP1's A-load (reads kv_b rows via afe; st_mlp1 body verified in r12).
// Deletes fused_b buffer + 512 staging blocks from stage2.
// r16 post-mortem: 64-row GEMM+LN fusions gave grid=48 on 256 CUs (81% idle).
// Fusion constraint set {row-ownership, weight-traffic, grid>=256} is
// unsatisfiable for N=256 GEMM+LN -> that direction is closed.
// LE=LA=2048, C=256, H=8, DH=32, DF=1024, n_remain=1024, Lq=3072, Lk=4096.

#define LE 2048
#define LA 2048
#define CDIM 256
#define HN 8
#define DH 32
#define DFF 1024
#define NREM 1024
#define LQC 3072
#define LKC 4096
#define KSPLIT 8
#define NIT (LKC / KSPLIT / 64)   // 8 iterations of 64 keys

typedef unsigned short u16;
typedef unsigned int u32;
typedef __attribute__((ext_vector_type(8))) short bf16x8;
typedef __attribute__((ext_vector_type(4))) float f32x4;

__device__ __forceinline__ u32 pk_bf16(float a, float b) {
    u32 ua = (__builtin_bit_cast(u32, a) + 0x8000u) >> 16;
    u32 ub = (__builtin_bit_cast(u32, b) + 0x8000u) >> 16;
    return ua | (ub << 16);
}
__device__ __forceinline__ u16 bf16_1(float a) {
    return (u16)((__builtin_bit_cast(u32, a) + 0x8000u) >> 16);
}
__device__ __forceinline__ float fast_exp2(float x) {
    return __builtin_amdgcn_exp2f(x);  // v_exp_f32: 2^x
}

// ----------------------------------------- hash-join matching (one block) --
__global__ __launch_bounds__(1024) void k_match(const int* __restrict__ pos_ego,
                                                const int* __restrict__ pos_agent,
                                                int* __restrict__ afe,
                                                int* __restrict__ matched,
                                                int* __restrict__ unmatched) {
    __shared__ int keyA[4096], valA[4096], keyE[4096];
    const int t = threadIdx.x;
#pragma unroll
    for (int i = 0; i < 4; ++i) { keyA[t + i * 1024] = -1; keyE[t + i * 1024] = -1; }
    __syncthreads();
#pragma unroll
    for (int i = 0; i < 2; ++i) {
        int a = t + i * 1024;
        int p = pos_agent[a];
        u32 h = ((u32)p * 2654435761u) >> 20;
        while (true) {
            int prev = atomicCAS(&keyA[h], -1, p);
            if (prev == -1) { valA[h] = a; break; }
            h = (h + 1) & 4095;
        }
        int e = t + i * 1024;
        int pe = pos_ego[e];
        u32 he = ((u32)pe * 2654435761u) >> 20;
        while (true) {
            int prev = atomicCAS(&keyE[he], -1, pe);
            if (prev == -1) break;
            he = (he + 1) & 4095;
        }
    }
    __syncthreads();
#pragma unroll
    for (int i = 0; i < 2; ++i) {
        int e = t + i * 1024;
        int p = pos_ego[e];
        u32 h = ((u32)p * 2654435761u) >> 20;
        int idx = 0, fnd = 0;
        while (true) {
            int k = keyA[h];
            if (k == p) { idx = valA[h]; fnd = 1; break; }
            if (k == -1) break;
            h = (h + 1) & 4095;
        }
        afe[e] = idx;
        matched[e] = fnd;
        int a = t + i * 1024;
        int pa_ = pos_agent[a];
        u32 ha = ((u32)pa_ * 2654435761u) >> 20;
        int fnd2 = 0;
        while (true) {
            int k = keyE[ha];
            if (k == pa_) { fnd2 = 1; break; }
            if (k == -1) break;
            ha = (ha + 1) & 4095;
        }
        unmatched[a] = !fnd2;
    }
}

// ----- fused stage2: scan(b0) + cvt_weights + kv staging (no build_fused) --
struct WPtrs { const float* p[7]; };
__constant__ __device__ const int woff[8] = {0, 131072, 196608, 262144,
                                             458752, 524288, 786432, 1048576};

__global__ __launch_bounds__(256) void k_stage2(const int* __restrict__ unmatched,
                                                int* __restrict__ remain,
                                                const float* __restrict__ x_ego,
                                                const float* __restrict__ x_agent,
                                                WPtrs wp, u16* __restrict__ wb,
                                                u16* __restrict__ kv_b) {
    int b = blockIdx.x;
    if (b == 0) {
        __shared__ int s[256];
        int t = threadIdx.x;
        int base_i = t * 8;
        int flags[8];
        int cnt = 0;
#pragma unroll
        for (int j = 0; j < 8; ++j) { flags[j] = unmatched[base_i + j]; cnt += flags[j]; }
        s[t] = cnt;
        __syncthreads();
        for (int off = 1; off < 256; off <<= 1) {
            int v = (t >= off) ? s[t - off] : 0;
            __syncthreads();
            s[t] += v;
            __syncthreads();
        }
        int pos = s[t] - cnt;
#pragma unroll
        for (int j = 0; j < 8; ++j) {
            if (flags[j]) {
                if (pos < NREM) remain[pos] = base_i + j;
                pos++;
            }
        }
    } else if (b <= 512) {
        int g = ((b - 1) * 256 + threadIdx.x) * 8;  // < 1048576
        int s = 0;
#pragma unroll
        for (int i = 1; i < 7; ++i) s += (g >= woff[i]);
        const float* src = wp.p[s] + (g - woff[s]);
        float4 f0 = *(const float4*)(src);
        float4 f1 = *(const float4*)(src + 4);
        uint4 o;
        o.x = pk_bf16(f0.x, f0.y); o.y = pk_bf16(f0.z, f0.w);
        o.z = pk_bf16(f1.x, f1.y); o.w = pk_bf16(f1.z, f1.w);
        *(uint4*)(wb + g) = o;
    } else {
        int t = (b - 513) * 256 + threadIdx.x;  // LKC*32
        int j = t >> 5, c8 = t & 31;
        const float* src = (j < LE) ? (x_ego + (size_t)j * CDIM)
                                    : (x_agent + (size_t)(j - LE) * CDIM);
        float4 f0 = *(const float4*)(src + c8 * 8);
        float4 f1 = *(const float4*)(src + c8 * 8 + 4);
        uint4 o;
        o.x = pk_bf16(f0.x, f0.y); o.y = pk_bf16(f0.z, f0.w);
        o.z = pk_bf16(f1.x, f1.y); o.w = pk_bf16(f1.z, f1.w);
        *(uint4*)(kv_b + (size_t)j * CDIM + c8 * 8) = o;
    }
}

// --------------------------------------------------------- bf16 MFMA GEMM --
// EPI: 0=f32, 1=bf16
template <int EPI, bool RELU>
__global__ __launch_bounds__(256) void gemm_bf16(const u16* __restrict__ A,
                                                 const u16* __restrict__ B,
                                                 const float* __restrict__ bias,
                                                 void* __restrict__ C,
                                                 int M, int N, int K) {
    const int tid = threadIdx.x;
    const int w = tid >> 6, lane = tid & 63;
    const int quad = lane >> 4, qi = lane & 15;
    const int wm = w >> 1, wn = w & 1;
    const int bm = blockIdx.y * 64, bn = blockIdx.x * 64;

    const u16* pa0 = A + (size_t)(bm + wm * 32 + qi) * K + quad * 8;
    const u16* pa1 = pa0 + (size_t)16 * K;
    const u16* pb0 = B + (size_t)(bn + wn * 32 + qi) * K + quad * 8;
    const u16* pb1 = pb0 + (size_t)16 * K;

    f32x4 acc00 = {0.f, 0.f, 0.f, 0.f}, acc01 = {0.f, 0.f, 0.f, 0.f};
    f32x4 acc10 = {0.f, 0.f, 0.f, 0.f}, acc11 = {0.f, 0.f, 0.f, 0.f};

#pragma unroll 4
    for (int k = 0; k < K; k += 32) {
        bf16x8 a0 = *(const bf16x8*)(pa0 + k);
        bf16x8 a1 = *(const bf16x8*)(pa1 + k);
        bf16x8 b0 = *(const bf16x8*)(pb0 + k);
        bf16x8 b1 = *(const bf16x8*)(pb1 + k);
        acc00 = __builtin_amdgcn_mfma_f32_16x16x32_bf16(a0, b0, acc00, 0, 0, 0);
        acc01 = __builtin_amdgcn_mfma_f32_16x16x32_bf16(a0, b1, acc01, 0, 0, 0);
        acc10 = __builtin_amdgcn_mfma_f32_16x16x32_bf16(a1, b0, acc10, 0, 0, 0);
        acc11 = __builtin_amdgcn_mfma_f32_16x16x32_bf16(a1, b1, acc11, 0, 0, 0);
    }

#pragma unroll
    for (int i = 0; i < 2; ++i) {
#pragma unroll
        for (int j = 0; j < 2; ++j) {
            f32x4 acc = (i == 0) ? (j == 0 ? acc00 : acc01) : (j == 0 ? acc10 : acc11);
            int n = bn + wn * 32 + j * 16 + qi;
            int mbase = bm + wm * 32 + i * 16 + quad * 4;
            float bs = bias[n];
            float v[4];
#pragma unroll
            for (int r = 0; r < 4; ++r) {
                float x = acc[r] + bs;
                if (RELU) x = fmaxf(x, 0.f);
                v[r] = x;
            }
            if (EPI == 0) {
                float* Cf = (float*)C;
#pragma unroll
                for (int r = 0; r < 4; ++r) Cf[(size_t)(mbase + r) * N + n] = v[r];
            } else {
                u16* Cb = (u16*)C;
#pragma unroll
                for (int r = 0; r < 4; ++r) Cb[(size_t)(mbase + r) * N + n] = bf16_1(v[r]);
            }
        }
    }
}

// ------------- MLP1: A = concat(kv_b[ego rows], kv_b[LE+afe]) bf16 ---------
// grid (4, 32). build_fused folded into the A-load (st_mlp1 body, verified r12).
__global__ __launch_bounds__(256) void k_mlp1(const u16* __restrict__ kv_b,
                                              const int* __restrict__ afe,
                                              const u16* __restrict__ Wf1_b,
                                              const float* __restrict__ bf1,
                                              u16* __restrict__ h1_b) {
    const int tid = threadIdx.x;
    const int w = tid >> 6, lane = tid & 63;
    const int quad = lane >> 4, qi = lane & 15;
    const int wm = w >> 1, wn = w & 1;
    const int bm = blockIdx.y * 64, bn = blockIdx.x * 64;
    int e0 = bm + wm * 32 + qi, e1 = e0 + 16;
    const u16* pe0 = kv_b + (size_t)e0 * CDIM + quad * 8;
    const u16* pe1 = kv_b + (size_t)e1 * CDIM + quad * 8;
    const u16* pg0 = kv_b + (size_t)(LE + afe[e0]) * CDIM + quad * 8;
    const u16* pg1 = kv_b + (size_t)(LE + afe[e1]) * CDIM + quad * 8;
    const u16* pb0 = Wf1_b + (size_t)(bn + wn * 32 + qi) * 512 + quad * 8;
    const u16* pb1 = pb0 + (size_t)16 * 512;

    f32x4 a00 = {0, 0, 0, 0}, a01 = {0, 0, 0, 0}, a10 = {0, 0, 0, 0}, a11 = {0, 0, 0, 0};
#pragma unroll 4
    for (int k = 0; k < 256; k += 32) {
        bf16x8 x0 = *(const bf16x8*)(pe0 + k);
        bf16x8 x1 = *(const bf16x8*)(pe1 + k);
        bf16x8 y0 = *(const bf16x8*)(pb0 + k);
        bf16x8 y1 = *(const bf16x8*)(pb1 + k);
        a00 = __builtin_amdgcn_mfma_f32_16x16x32_bf16(x0, y0, a00, 0, 0, 0);
        a01 = __builtin_amdgcn_mfma_f32_16x16x32_bf16(x0, y1, a01, 0, 0, 0);
        a10 = __builtin_amdgcn_mfma_f32_16x16x32_bf16(x1, y0, a10, 0, 0, 0);
        a11 = __builtin_amdgcn_mfma_f32_16x16x32_bf16(x1, y1, a11, 0, 0, 0);
    }
#pragma unroll 4
    for (int k = 0; k < 256; k += 32) {
        bf16x8 x0 = *(const bf16x8*)(pg0 + k);
        bf16x8 x1 = *(const bf16x8*)(pg1 + k);
        bf16x8 y0 = *(const bf16x8*)(pb0 + 256 + k);
        bf16x8 y1 = *(const bf16x8*)(pb1 + 256 + k);
        a00 = __builtin_amdgcn_mfma_f32_16x16x32_bf16(x0, y0, a00, 0, 0, 0);
        a01 = __builtin_amdgcn_mfma_f32_16x16x32_bf16(x0, y1, a01, 0, 0, 0);
        a10 = __builtin_amdgcn_mfma_f32_16x16x32_bf16(x1, y0, a10, 0, 0, 0);
        a11 = __builtin_amdgcn_mfma_f32_16x16x32_bf16(x1, y1, a11, 0, 0, 0);
    }
#pragma unroll
    for (int i = 0; i < 2; ++i)
#pragma unroll
        for (int jj = 0; jj < 2; ++jj) {
            f32x4 acc = (i == 0) ? (jj == 0 ? a00 : a01) : (jj == 0 ? a10 : a11);
            int n = bn + wn * 32 + jj * 16 + qi;
            int mb = bm + wm * 32 + i * 16 + quad * 4;
            float bs = bf1[n];
#pragma unroll
            for (int r = 0; r < 4; ++r)
                h1_b[(size_t)(mb + r) * 256 + n] = bf16_1(fmaxf(acc[r] + bs, 0.f));
        }
}

// ------- MLP3 + finalize: qbuf = select(matched, mlp, x_ego) + gather ------
__global__ __launch_bounds__(256) void k_mlp3f(const u16* __restrict__ h2_b,
                                               const u16* __restrict__ Wf3_b,
                                               const float* __restrict__ bf3,
                                               const int* __restrict__ matched,
                                               const int* __restrict__ remain,
                                               const float* __restrict__ x_ego,
                                               const float* __restrict__ x_agent,
                                               float* __restrict__ qbuf,
                                               u16* __restrict__ qbuf_b) {
    const int tid = threadIdx.x;
    const int bn = blockIdx.x * 64, bm = blockIdx.y * 64;
    if (bm >= LE) {  // gather rows LE..LQC
        int row = bm + (tid >> 2);
        int col = bn + (tid & 3) * 16;
        int idx = remain[row - LE];
        idx = min(max(idx, 0), LA - 1);
        const float* src = x_agent + (size_t)idx * CDIM + col;
        float* dq = qbuf + (size_t)row * CDIM + col;
        u16* db = qbuf_b + (size_t)row * CDIM + col;
#pragma unroll
        for (int i = 0; i < 4; ++i) {
            float4 v = *(const float4*)(src + i * 4);
            *(float4*)(dq + i * 4) = v;
            *(uint2*)(db + i * 4) = make_uint2(pk_bf16(v.x, v.y), pk_bf16(v.z, v.w));
        }
        return;
    }
    const int w = tid >> 6, lane = tid & 63;
    const int quad = lane >> 4, qi = lane & 15;
    const int wm = w >> 1, wn = w & 1;
    const u16* pa0 = h2_b + (size_t)(bm + wm * 32 + qi) * 256 + quad * 8;
    const u16* pa1 = pa0 + (size_t)16 * 256;
    const u16* pb0 = Wf3_b + (size_t)(bn + wn * 32 + qi) * 256 + quad * 8;
    const u16* pb1 = pb0 + (size_t)16 * 256;
    f32x4 a00 = {0, 0, 0, 0}, a01 = {0, 0, 0, 0}, a10 = {0, 0, 0, 0}, a11 = {0, 0, 0, 0};
#pragma unroll 4
    for (int k = 0; k < 256; k += 32) {
        bf16x8 x0 = *(const bf16x8*)(pa0 + k);
        bf16x8 x1 = *(const bf16x8*)(pa1 + k);
        bf16x8 y0 = *(const bf16x8*)(pb0 + k);
        bf16x8 y1 = *(const bf16x8*)(pb1 + k);
        a00 = __builtin_amdgcn_mfma_f32_16x16x32_bf16(x0, y0, a00, 0, 0, 0);
        a01 = __builtin_amdgcn_mfma_f32_16x16x32_bf16(x0, y1, a01, 0, 0, 0);
        a10 = __builtin_amdgcn_mfma_f32_16x16x32_bf16(x1, y0, a10, 0, 0, 0);
        a11 = __builtin_amdgcn_mfma_f32_16x16x32_bf16(x1, y1, a11, 0, 0, 0);
    }
#pragma unroll
    for (int i = 0; i < 2; ++i)
#pragma unroll
        for (int jj = 0; jj < 2; ++jj) {
            f32x4 acc = (i == 0) ? (jj == 0 ? a00 : a01) : (jj == 0 ? a10 : a11);
            int n = bn + wn * 32 + jj * 16 + qi;
            int mb = bm + wm * 32 + i * 16 + quad * 4;
            float bs = bf3[n];
#pragma unroll
            for (int r = 0; r < 4; ++r) {
                int row = mb + r;
                float v = acc[r] + bs;
                if (!matched[row]) v = x_ego[(size_t)row * CDIM + n];
                qbuf[(size_t)row * CDIM + n] = v;
                qbuf_b[(size_t)row * CDIM + n] = bf16_1(v);
            }
        }
}

// --------------------------- fused QKV projection (one dispatch) -----------
__global__ __launch_bounds__(256) void k_qkv(const u16* __restrict__ qbuf_b,
                                             const u16* __restrict__ kv_b,
                                             const u16* __restrict__ Wq,
                                             const u16* __restrict__ Wkv,
                                             const float* __restrict__ bqkv,
                                             u16* __restrict__ qb,
                                             u16* __restrict__ kbp,
                                             u16* __restrict__ vtb,
                                             float qscale) {
    int b = blockIdx.x;
    const u16 *A, *B;
    const float* bias;
    int bm, bn, mode;
    if (b < 192) {
        A = qbuf_b; B = Wq; bias = bqkv;
        bm = (b >> 2) * 64; bn = (b & 3) * 64; mode = 0;
    } else {
        int c = b - 192;
        A = kv_b; B = Wkv; bias = bqkv + 256;
        bm = (c >> 3) * 64; bn = (c & 7) * 64; mode = 1;
    }
    const int tid = threadIdx.x;
    const int w = tid >> 6, lane = tid & 63;
    const int quad = lane >> 4, qi = lane & 15;
    const int wm = w >> 1, wn = w & 1;
    const int K = 256;

    const u16* pa0 = A + (size_t)(bm + wm * 32 + qi) * K + quad * 8;
    const u16* pa1 = pa0 + (size_t)16 * K;
    const u16* pb0 = B + (size_t)(bn + wn * 32 + qi) * K + quad * 8;
    const u16* pb1 = pb0 + (size_t)16 * K;

    f32x4 acc00 = {0.f, 0.f, 0.f, 0.f}, acc01 = {0.f, 0.f, 0.f, 0.f};
    f32x4 acc10 = {0.f, 0.f, 0.f, 0.f}, acc11 = {0.f, 0.f, 0.f, 0.f};
#pragma unroll 4
    for (int k = 0; k < 256; k += 32) {
        bf16x8 a0 = *(const bf16x8*)(pa0 + k);
        bf16x8 a1 = *(const bf16x8*)(pa1 + k);
        bf16x8 b0 = *(const bf16x8*)(pb0 + k);
        bf16x8 b1 = *(const bf16x8*)(pb1 + k);
        acc00 = __builtin_amdgcn_mfma_f32_16x16x32_bf16(a0, b0, acc00, 0, 0, 0);
        acc01 = __builtin_amdgcn_mfma_f32_16x16x32_bf16(a0, b1, acc01, 0, 0, 0);
        acc10 = __builtin_amdgcn_mfma_f32_16x16x32_bf16(a1, b0, acc10, 0, 0, 0);
        acc11 = __builtin_amdgcn_mfma_f32_16x16x32_bf16(a1, b1, acc11, 0, 0, 0);
    }
#pragma unroll
    for (int i = 0; i < 2; ++i) {
#pragma unroll
        for (int j = 0; j < 2; ++j) {
            f32x4 acc = (i == 0) ? (j == 0 ? acc00 : acc01) : (j == 0 ? acc10 : acc11);
            int n = bn + wn * 32 + j * 16 + qi;
            int mbase = bm + wm * 32 + i * 16 + quad * 4;
            float bs = bias[n];
            float v[4];
#pragma unroll
            for (int r = 0; r < 4; ++r) v[r] = acc[r] + bs;
            if (mode == 0) {
#pragma unroll
                for (int r = 0; r < 4; ++r)
                    qb[(size_t)(mbase + r) * 256 + n] = bf16_1(v[r] * qscale);
            } else if (n < 256) {
#pragma unroll
                for (int r = 0; r < 4; ++r)
                    kbp[(size_t)(mbase + r) * 256 + n] = bf16_1(v[r]);
            } else {
                ushort4 o4;
                o4.x = bf16_1(v[0]); o4.y = bf16_1(v[1]);
                o4.z = bf16_1(v[2]); o4.w = bf16_1(v[3]);
                *(ushort4*)(vtb + (size_t)(n - 256) * LKC + mbase) = o4;
            }
        }
    }
}

// --------------------------- MFMA attention, LDS-staged K/V tiles ----------
__global__ __launch_bounds__(256) void attn_mfma(const u16* __restrict__ qb,
                                                 const u16* __restrict__ kb,
                                                 const u16* __restrict__ vtb,
                                                 float* __restrict__ Pl,
                                                 float* __restrict__ Pacc) {
    __shared__ u16 Kt[2][64 * 32];
    __shared__ u16 Vt[2][32 * 64];
    __shared__ u16 plds[4][16 * 64];
    const int tid = threadIdx.x;
    const int w = tid >> 6, lane = tid & 63;
    const int quad = lane >> 4, qi = lane & 15;
    const int h = blockIdx.y, ks = blockIdx.z;
    const int q0 = blockIdx.x * 64 + w * 16;

    bf16x8 qf = *(const bf16x8*)(qb + (size_t)(q0 + qi) * CDIM + h * DH + quad * 8);

    f32x4 O0 = {0.f, 0.f, 0.f, 0.f}, O1 = {0.f, 0.f, 0.f, 0.f};
    float lsum = 0.f;

    const int krow = w * 16 + (lane >> 2), kcp = lane & 3;
    const int kc = kcp ^ (krow & 3);
    const u16* kg0 = kb + (size_t)krow * CDIM + h * DH + kc * 8;
    const int kdst = krow * 32 + kcp * 8;
    const int vd = w * 8 + (lane >> 3), vcp = lane & 7;
    const int vc = vcp ^ (vd & 7);
    const u16* vg0 = vtb + (size_t)(h * DH + vd) * LKC + vc * 8;
    const int vdst = vd * 64 + vcp * 8;

    const int ka0 = qi * 32 + ((quad ^ (qi & 3)) << 3);
    const int v00o = qi * 64 + ((quad ^ (qi & 7)) << 3);
    const int v01o = qi * 64 + (((quad + 4) ^ (qi & 7)) << 3);
    const int swz = (qi & 7);
    const int rd0 = qi * 64 + ((quad ^ swz) << 3);
    const int rd1 = qi * 64 + (((4 + quad) ^ swz) << 3);
    const int half = (quad & 1) << 2;

    int kt = ks * (LKC / KSPLIT);
    {
        bf16x8 kr = *(const bf16x8*)(kg0 + (size_t)kt * CDIM);
        bf16x8 vr = *(const bf16x8*)(vg0 + kt);
        *(bf16x8*)&Kt[0][kdst] = kr;
        *(bf16x8*)&Vt[0][vdst] = vr;
    }
    int buf = 0;
    for (int it = 0; it < NIT; ++it, kt += 64) {
        __syncthreads();
        bf16x8 knext, vnext;
        const bool more = (it + 1 < NIT);
        if (more) {
            knext = *(const bf16x8*)(kg0 + (size_t)(kt + 64) * CDIM);
            vnext = *(const bf16x8*)(vg0 + kt + 64);
        }

        bf16x8 a0 = *(const bf16x8*)&Kt[buf][ka0];
        bf16x8 a1 = *(const bf16x8*)&Kt[buf][ka0 + 16 * 32];
        bf16x8 a2 = *(const bf16x8*)&Kt[buf][ka0 + 32 * 32];
        bf16x8 a3 = *(const bf16x8*)&Kt[buf][ka0 + 48 * 32];
        f32x4 z = {0.f, 0.f, 0.f, 0.f};
        f32x4 s0 = __builtin_amdgcn_mfma_f32_16x16x32_bf16(a0, qf, z, 0, 0, 0);
        f32x4 s1 = __builtin_amdgcn_mfma_f32_16x16x32_bf16(a1, qf, z, 0, 0, 0);
        f32x4 s2 = __builtin_amdgcn_mfma_f32_16x16x32_bf16(a2, qf, z, 0, 0, 0);
        f32x4 s3 = __builtin_amdgcn_mfma_f32_16x16x32_bf16(a3, qf, z, 0, 0, 0);

        float p0[4], p1[4], p2[4], p3[4];
#pragma unroll
        for (int r = 0; r < 4; ++r) {
            p0[r] = fast_exp2(s0[r]); p1[r] = fast_exp2(s1[r]);
            p2[r] = fast_exp2(s2[r]); p3[r] = fast_exp2(s3[r]);
            lsum += p0[r] + p1[r] + p2[r] + p3[r];
        }

        u16* pb = &plds[w][0];
#pragma unroll
        for (int t2 = 0; t2 < 4; ++t2) {
            int jg = t2 * 2 + (quad >> 1);
            int off = qi * 64 + ((jg ^ swz) << 3) + half;
            uint2 pw;
            float* pp = (t2 == 0) ? p0 : (t2 == 1) ? p1 : (t2 == 2) ? p2 : p3;
            pw.x = pk_bf16(pp[0], pp[1]);
            pw.y = pk_bf16(pp[2], pp[3]);
            *(uint2*)&pb[off] = pw;
        }
        bf16x8 pa0 = *(bf16x8*)&pb[rd0];
        bf16x8 pa1 = *(bf16x8*)&pb[rd1];

        bf16x8 v00 = *(const bf16x8*)&Vt[buf][v00o];
        bf16x8 v01 = *(const bf16x8*)&Vt[buf][v01o];
        bf16x8 v10 = *(const bf16x8*)&Vt[buf][v00o + 16 * 64];
        bf16x8 v11 = *(const bf16x8*)&Vt[buf][v01o + 16 * 64];
        O0 = __builtin_amdgcn_mfma_f32_16x16x32_bf16(pa0, v00, O0, 0, 0, 0);
        O0 = __builtin_amdgcn_mfma_f32_16x16x32_bf16(pa1, v01, O0, 0, 0, 0);
        O1 = __builtin_amdgcn_mfma_f32_16x16x32_bf16(pa0, v10, O1, 0, 0, 0);
        O1 = __builtin_amdgcn_mfma_f32_16x16x32_bf16(pa1, v11, O1, 0, 0, 0);

        if (more) {
            *(bf16x8*)&Kt[buf ^ 1][kdst] = knext;
            *(bf16x8*)&Vt[buf ^ 1][vdst] = vnext;
        }
        buf ^= 1;
    }

    lsum += __shfl_xor(lsum, 16, 64);
    lsum += __shfl_xor(lsum, 32, 64);

    int pbase = (h * KSPLIT + ks) * LQC + q0;
    if (quad == 0) Pl[pbase + qi] = lsum;
#pragma unroll
    for (int r = 0; r < 4; ++r) {
        int q = quad * 4 + r;
        float* pa = Pacc + (size_t)(pbase + q) * 32;
        pa[qi] = O0[r];
        pa[16 + qi] = O1[r];
    }
}

__global__ __launch_bounds__(256) void attn_combine(const float* __restrict__ Pl,
                                                    const float* __restrict__ Pacc,
                                                    u16* __restrict__ attn_b) {
    int t = blockIdx.x * 256 + threadIdx.x;  // LQC*64
    int row = t >> 6;
    int h = (t >> 3) & 7;
    int d4 = t & 7;
    float L = 0.f;
    float o[4] = {};
#pragma unroll
    for (int ck = 0; ck < KSPLIT; ++ck) {
        size_t pidx = (size_t)(h * KSPLIT + ck) * LQC + row;
        L += Pl[pidx];
        float4 a = *(const float4*)(Pacc + pidx * 32 + d4 * 4);
        o[0] += a.x; o[1] += a.y; o[2] += a.z; o[3] += a.w;
    }
    float inv = 1.0f / L;
    ushort4 ov;
    ov.x = bf16_1(o[0] * inv); ov.y = bf16_1(o[1] * inv);
    ov.z = bf16_1(o[2] * inv); ov.w = bf16_1(o[3] * inv);
    *(ushort4*)(attn_b + (size_t)row * CDIM + h * DH + d4 * 4) = ov;
}

// -------------------------------------------------------------- layernorm --
template <bool EMIT_BF16>
__global__ __launch_bounds__(256) void ln_kernel(const float* __restrict__ X,
                                                 const float* __restrict__ R,
                                                 const float* __restrict__ g,
                                                 const float* __restrict__ b,
                                                 float* __restrict__ out,
                                                 u16* __restrict__ out_b) {
    int lane = threadIdx.x & 63;
    int row = blockIdx.x * 4 + (threadIdx.x >> 6);
    const float* x = X + (size_t)row * CDIM;
    const float* r = R + (size_t)row * CDIM;
    float4 xv = *(const float4*)(x + lane * 4);
    float4 rv = *(const float4*)(r + lane * 4);
    float v[4] = {xv.x + rv.x, xv.y + rv.y, xv.z + rv.z, xv.w + rv.w};
    float s = v[0] + v[1] + v[2] + v[3];
    float sq = v[0] * v[0] + v[1] * v[1] + v[2] * v[2] + v[3] * v[3];
#pragma unroll
    for (int off = 32; off >= 1; off >>= 1) {
        s += __shfl_xor(s, off, 64);
        sq += __shfl_xor(sq, off, 64);
    }
    float mean = s * (1.f / 256.f);
    float var = sq * (1.f / 256.f) - mean * mean;
    float rstd = rsqrtf(var + 1e-5f);
    float4 gv = *(const float4*)(g + lane * 4);
    float4 bv = *(const float4*)(b + lane * 4);
    float4 o = make_float4((v[0] - mean) * rstd * gv.x + bv.x,
                           (v[1] - mean) * rstd * gv.y + bv.y,
                           (v[2] - mean) * rstd * gv.z + bv.z,
                           (v[3] - mean) * rstd * gv.w + bv.w);
    *(float4*)(out + (size_t)row * CDIM + lane * 4) = o;
    if (EMIT_BF16) {
        uint2 ob;
        ob.x = pk_bf16(o.x, o.y);
        ob.y = pk_bf16(o.z, o.w);
        *(uint2*)(out_b + (size_t)row * CDIM + lane * 4) = ob;
    }
}

// ------------------------------------------------------------------ launch --
extern "C" void kernel_launch(void* const* d_in, const int* in_sizes, int n_in,
                              void* d_out, int out_size, void* d_ws, size_t ws_size,
                              hipStream_t stream) {
    const float* x_ego = (const float*)d_in[0];
    const float* x_agent = (const float*)d_in[1];
    const float* Wf1 = (const float*)d_in[2];
    const float* bf1 = (const float*)d_in[3];
    const float* Wf2 = (const float*)d_in[4];
    const float* bf2 = (const float*)d_in[5];
    const float* Wf3 = (const float*)d_in[6];
    const float* bf3 = (const float*)d_in[7];
    const float* Wqkv = (const float*)d_in[8];
    const float* bqkv = (const float*)d_in[9];
    const float* Wo = (const float*)d_in[10];
    const float* bo = (const float*)d_in[11];
    const float* W1 = (const float*)d_in[12];
    const float* b1 = (const float*)d_in[13];
    const float* W2 = (const float*)d_in[14];
    const float* b2 = (const float*)d_in[15];
    const float* g1 = (const float*)d_in[16];
    const float* be1 = (const float*)d_in[17];
    const float* g2 = (const float*)d_in[18];
    const float* be2 = (const float*)d_in[19];
    const int* pos_ego = (const int*)d_in[20];
    const int* pos_agent = (const int*)d_in[21];

    float* ws = (float*)d_ws;
    size_t o = 0;
    float* qbuf = ws + o; o += 786432;
    float* o2 = ws + o; o += 786432;
    float* yq = ws + o; o += 786432;
    float* ff2 = o2;  // o2 consumed by ln1 before ffn2 writes ff2
    float* Pl = ws + o; o += HN * KSPLIT * LQC;                 // 196608
    float* Pacc = ws + o; o += (size_t)HN * KSPLIT * LQC * 32;  // 6291456
    u16* wb = (u16*)(ws + o); o += 524288;        // 1,048,576 u16
    u16* h1_b = (u16*)(ws + o); o += 262144;      // LE*256
    u16* h2_b = (u16*)(ws + o); o += 262144;
    u16* qbuf_b = (u16*)(ws + o); o += 393216;    // LQC*256
    u16* kv_b = (u16*)(ws + o); o += 524288;      // LKC*256
    u16* qb = (u16*)(ws + o); o += 393216;
    u16* kb = (u16*)(ws + o); o += 524288;
    u16* vtb = (u16*)(ws + o); o += 524288;
    u16* attn_b = (u16*)(ws + o); o += 393216;
    u16* ff1_b = (u16*)(ws + o); o += 1572864;    // LQC*1024
    u16* yq_b = (u16*)(ws + o); o += 393216;
    int* afe = (int*)(ws + o);
    int* matched = afe + LE;
    int* unmatched = matched + LE;
    int* remain = unmatched + LA;

    const u16* Wf1_b = wb + 0;
    const u16* Wf2_b = wb + 131072;
    const u16* Wf3_b = wb + 196608;
    const u16* Wq_b = wb + 262144;
    const u16* Wkv_b = wb + 327680;
    const u16* Wo_b = wb + 458752;
    const u16* W1_b = wb + 524288;
    const u16* W2_b = wb + 786432;

    // 1. matching (LDS hash join)
    k_match<<<1, 1024, 0, stream>>>(pos_ego, pos_agent, afe, matched, unmatched);
    WPtrs wp;
    wp.p[0] = Wf1; wp.p[1] = Wf2; wp.p[2] = Wf3; wp.p[3] = Wqkv;
    wp.p[4] = Wo; wp.p[5] = W1; wp.p[6] = W2;
    // 2. stage2: scan + weight cvt + kv staging (build_fused removed)
    k_stage2<<<1025, 256, 0, stream>>>(unmatched, remain, x_ego, x_agent, wp, wb, kv_b);

    const float qscale = 0.17677669529663687f * 1.4426950408889634f;

    // 3-5. fusion MLP (concat A-load folded into MLP1; finalize in MLP3)
    k_mlp1<<<dim3(4, 32), 256, 0, stream>>>(kv_b, afe, Wf1_b, bf1, h1_b);
    gemm_bf16<1, true><<<dim3(4, 32), 256, 0, stream>>>(h1_b, Wf2_b, bf2, h2_b,
                                                        LE, 256, 256);
    k_mlp3f<<<dim3(4, 48), 256, 0, stream>>>(h2_b, Wf3_b, bf3, matched, remain,
                                             x_ego, x_agent, qbuf, qbuf_b);

    // 6. fused QKV projections
    k_qkv<<<704, 256, 0, stream>>>(qbuf_b, kv_b, Wq_b, Wkv_b, bqkv, qb, kb, vtb, qscale);

    // 7. attention (KSPLIT=8)
    attn_mfma<<<dim3(LQC / 64, HN, KSPLIT), 256, 0, stream>>>(qb, kb, vtb, Pl, Pacc);
    // 8. combine
    attn_combine<<<(LQC * 64) / 256, 256, 0, stream>>>(Pl, Pacc, attn_b);

    // 9-10. out-proj + LN1
    gemm_bf16<0, false><<<dim3(4, 48), 256, 0, stream>>>(attn_b, Wo_b, bo, o2,
                                                         LQC, 256, 256);
    ln_kernel<true><<<LQC / 4, 256, 0, stream>>>(qbuf, o2, g1, be1, yq, yq_b);

    // 11-13. FFN + LN2
    gemm_bf16<1, true><<<dim3(16, 48), 256, 0, stream>>>(yq_b, W1_b, b1, ff1_b,
                                                         LQC, DFF, 256);
    gemm_bf16<0, false><<<dim3(4, 48), 256, 0, stream>>>(ff1_b, W2_b, b2, ff2,
                                                         LQC, 256, DFF);
    ln_kernel<false><<<LQC / 4, 256, 0, stream>>>(yq, ff2, g2, be2, (float*)d_out, nullptr);
}

// Round 18
// 216.687 us; speedup vs baseline: 1.1575x; 1.0135x over previous
//
#include <hip/hip_runtime.h>

// FeatureMagnet FINAL (r14 champion, 216.7us measured): ego/agent hash-join
// matching + bf16 MFMA fusion MLP + fused QKV proj + LDS-tiled flash
// attention (KSPLIT=8, no-max exp2 softmax) + tiled out-proj/FFN + LNs.
// Session: 757us (r1 fp32) -> 216.7us. Remaining ~110us is dispatch-boundary
// cost; coop-sync (60us/barrier), monolithic dispatch (occupancy loss), and
// cross-kernel fusion (traffic/grid tradeoff) all measured worse.
// LE=LA=2048, C=256, H=8, DH=32, DF=1024, n_remain=1024, Lq=3072, Lk=4096.

#define LE 2048
#define LA 2048
#define CDIM 256
#define HN 8
#define DH 32
#define DFF 1024
#define NREM 1024
#define LQC 3072
#define LKC 4096
#define KSPLIT 8
#define NIT (LKC / KSPLIT / 64)   // 8 iterations of 64 keys

typedef unsigned short u16;
typedef unsigned int u32;
typedef __attribute__((ext_vector_type(8))) short bf16x8;
typedef __attribute__((ext_vector_type(4))) float f32x4;

__device__ __forceinline__ u32 pk_bf16(float a, float b) {
    u32 ua = (__builtin_bit_cast(u32, a) + 0x8000u) >> 16;
    u32 ub = (__builtin_bit_cast(u32, b) + 0x8000u) >> 16;
    return ua | (ub << 16);
}
__device__ __forceinline__ u16 bf16_1(float a) {
    return (u16)((__builtin_bit_cast(u32, a) + 0x8000u) >> 16);
}
__device__ __forceinline__ float fast_exp2(float x) {
    return __builtin_amdgcn_exp2f(x);  // v_exp_f32: 2^x
}

// ----------------------------------------- hash-join matching (one block) --
__global__ __launch_bounds__(1024) void k_match(const int* __restrict__ pos_ego,
                                                const int* __restrict__ pos_agent,
                                                int* __restrict__ afe,
                                                int* __restrict__ matched,
                                                int* __restrict__ unmatched) {
    __shared__ int keyA[4096], valA[4096], keyE[4096];
    const int t = threadIdx.x;
#pragma unroll
    for (int i = 0; i < 4; ++i) { keyA[t + i * 1024] = -1; keyE[t + i * 1024] = -1; }
    __syncthreads();
#pragma unroll
    for (int i = 0; i < 2; ++i) {
        int a = t + i * 1024;
        int p = pos_agent[a];
        u32 h = ((u32)p * 2654435761u) >> 20;
        while (true) {
            int prev = atomicCAS(&keyA[h], -1, p);
            if (prev == -1) { valA[h] = a; break; }
            h = (h + 1) & 4095;
        }
        int e = t + i * 1024;
        int pe = pos_ego[e];
        u32 he = ((u32)pe * 2654435761u) >> 20;
        while (true) {
            int prev = atomicCAS(&keyE[he], -1, pe);
            if (prev == -1) break;
            he = (he + 1) & 4095;
        }
    }
    __syncthreads();
#pragma unroll
    for (int i = 0; i < 2; ++i) {
        int e = t + i * 1024;
        int p = pos_ego[e];
        u32 h = ((u32)p * 2654435761u) >> 20;
        int idx = 0, fnd = 0;
        while (true) {
            int k = keyA[h];
            if (k == p) { idx = valA[h]; fnd = 1; break; }
            if (k == -1) break;
            h = (h + 1) & 4095;
        }
        afe[e] = idx;
        matched[e] = fnd;
        int a = t + i * 1024;
        int pa_ = pos_agent[a];
        u32 ha = ((u32)pa_ * 2654435761u) >> 20;
        int fnd2 = 0;
        while (true) {
            int k = keyE[ha];
            if (k == pa_) { fnd2 = 1; break; }
            if (k == -1) break;
            ha = (ha + 1) & 4095;
        }
        unmatched[a] = !fnd2;
    }
}

// ----- fused stage2: scan(b0) + build_fused + cvt_weights + kv staging -----
struct WPtrs { const float* p[7]; };
__constant__ __device__ const int woff[8] = {0, 131072, 196608, 262144,
                                             458752, 524288, 786432, 1048576};

__global__ __launch_bounds__(256) void k_stage2(const int* __restrict__ unmatched,
                                                int* __restrict__ remain,
                                                const int* __restrict__ afe,
                                                const float* __restrict__ x_ego,
                                                const float* __restrict__ x_agent,
                                                u16* __restrict__ fused_b,
                                                WPtrs wp, u16* __restrict__ wb,
                                                u16* __restrict__ kv_b) {
    int b = blockIdx.x;
    if (b == 0) {
        __shared__ int s[256];
        int t = threadIdx.x;
        int base_i = t * 8;
        int flags[8];
        int cnt = 0;
#pragma unroll
        for (int j = 0; j < 8; ++j) { flags[j] = unmatched[base_i + j]; cnt += flags[j]; }
        s[t] = cnt;
        __syncthreads();
        for (int off = 1; off < 256; off <<= 1) {
            int v = (t >= off) ? s[t - off] : 0;
            __syncthreads();
            s[t] += v;
            __syncthreads();
        }
        int pos = s[t] - cnt;
#pragma unroll
        for (int j = 0; j < 8; ++j) {
            if (flags[j]) {
                if (pos < NREM) remain[pos] = base_i + j;
                pos++;
            }
        }
    } else if (b <= 512) {
        int t = (b - 1) * 256 + threadIdx.x;  // LE*64
        int e = t >> 6, c8 = t & 63;
        const float* src;
        int col;
        if (c8 < 32) { src = x_ego + (size_t)e * CDIM; col = c8 * 8; }
        else { src = x_agent + (size_t)afe[e] * CDIM; col = (c8 - 32) * 8; }
        float4 f0 = *(const float4*)(src + col);
        float4 f1 = *(const float4*)(src + col + 4);
        uint4 o;
        o.x = pk_bf16(f0.x, f0.y); o.y = pk_bf16(f0.z, f0.w);
        o.z = pk_bf16(f1.x, f1.y); o.w = pk_bf16(f1.z, f1.w);
        *(uint4*)(fused_b + (size_t)e * 512 + c8 * 8) = o;
    } else if (b <= 1024) {
        int g = ((b - 513) * 256 + threadIdx.x) * 8;  // < 1048576
        int s = 0;
#pragma unroll
        for (int i = 1; i < 7; ++i) s += (g >= woff[i]);
        const float* src = wp.p[s] + (g - woff[s]);
        float4 f0 = *(const float4*)(src);
        float4 f1 = *(const float4*)(src + 4);
        uint4 o;
        o.x = pk_bf16(f0.x, f0.y); o.y = pk_bf16(f0.z, f0.w);
        o.z = pk_bf16(f1.x, f1.y); o.w = pk_bf16(f1.z, f1.w);
        *(uint4*)(wb + g) = o;
    } else {
        int t = (b - 1025) * 256 + threadIdx.x;  // LKC*32
        int j = t >> 5, c8 = t & 31;
        const float* src = (j < LE) ? (x_ego + (size_t)j * CDIM)
                                    : (x_agent + (size_t)(j - LE) * CDIM);
        float4 f0 = *(const float4*)(src + c8 * 8);
        float4 f1 = *(const float4*)(src + c8 * 8 + 4);
        uint4 o;
        o.x = pk_bf16(f0.x, f0.y); o.y = pk_bf16(f0.z, f0.w);
        o.z = pk_bf16(f1.x, f1.y); o.w = pk_bf16(f1.z, f1.w);
        *(uint4*)(kv_b + (size_t)j * CDIM + c8 * 8) = o;
    }
}

// --------------------------------------------------------- bf16 MFMA GEMM --
// EPI: 0=f32, 1=bf16
template <int EPI, bool RELU>
__global__ __launch_bounds__(256) void gemm_bf16(const u16* __restrict__ A,
                                                 const u16* __restrict__ B,
                                                 const float* __restrict__ bias,
                                                 void* __restrict__ C,
                                                 int M, int N, int K) {
    const int tid = threadIdx.x;
    const int w = tid >> 6, lane = tid & 63;
    const int quad = lane >> 4, qi = lane & 15;
    const int wm = w >> 1, wn = w & 1;
    const int bm = blockIdx.y * 64, bn = blockIdx.x * 64;

    const u16* pa0 = A + (size_t)(bm + wm * 32 + qi) * K + quad * 8;
    const u16* pa1 = pa0 + (size_t)16 * K;
    const u16* pb0 = B + (size_t)(bn + wn * 32 + qi) * K + quad * 8;
    const u16* pb1 = pb0 + (size_t)16 * K;

    f32x4 acc00 = {0.f, 0.f, 0.f, 0.f}, acc01 = {0.f, 0.f, 0.f, 0.f};
    f32x4 acc10 = {0.f, 0.f, 0.f, 0.f}, acc11 = {0.f, 0.f, 0.f, 0.f};

#pragma unroll 4
    for (int k = 0; k < K; k += 32) {
        bf16x8 a0 = *(const bf16x8*)(pa0 + k);
        bf16x8 a1 = *(const bf16x8*)(pa1 + k);
        bf16x8 b0 = *(const bf16x8*)(pb0 + k);
        bf16x8 b1 = *(const bf16x8*)(pb1 + k);
        acc00 = __builtin_amdgcn_mfma_f32_16x16x32_bf16(a0, b0, acc00, 0, 0, 0);
        acc01 = __builtin_amdgcn_mfma_f32_16x16x32_bf16(a0, b1, acc01, 0, 0, 0);
        acc10 = __builtin_amdgcn_mfma_f32_16x16x32_bf16(a1, b0, acc10, 0, 0, 0);
        acc11 = __builtin_amdgcn_mfma_f32_16x16x32_bf16(a1, b1, acc11, 0, 0, 0);
    }

#pragma unroll
    for (int i = 0; i < 2; ++i) {
#pragma unroll
        for (int j = 0; j < 2; ++j) {
            f32x4 acc = (i == 0) ? (j == 0 ? acc00 : acc01) : (j == 0 ? acc10 : acc11);
            int n = bn + wn * 32 + j * 16 + qi;
            int mbase = bm + wm * 32 + i * 16 + quad * 4;
            float bs = bias[n];
            float v[4];
#pragma unroll
            for (int r = 0; r < 4; ++r) {
                float x = acc[r] + bs;
                if (RELU) x = fmaxf(x, 0.f);
                v[r] = x;
            }
            if (EPI == 0) {
                float* Cf = (float*)C;
#pragma unroll
                for (int r = 0; r < 4; ++r) Cf[(size_t)(mbase + r) * N + n] = v[r];
            } else {
                u16* Cb = (u16*)C;
#pragma unroll
                for (int r = 0; r < 4; ++r) Cb[(size_t)(mbase + r) * N + n] = bf16_1(v[r]);
            }
        }
    }
}

// ------- MLP3 + finalize: qbuf = select(matched, mlp, x_ego) + gather ------
__global__ __launch_bounds__(256) void k_mlp3f(const u16* __restrict__ h2_b,
                                               const u16* __restrict__ Wf3_b,
                                               const float* __restrict__ bf3,
                                               const int* __restrict__ matched,
                                               const int* __restrict__ remain,
                                               const float* __restrict__ x_ego,
                                               const float* __restrict__ x_agent,
                                               float* __restrict__ qbuf,
                                               u16* __restrict__ qbuf_b) {
    const int tid = threadIdx.x;
    const int bn = blockIdx.x * 64, bm = blockIdx.y * 64;
    if (bm >= LE) {  // gather rows LE..LQC
        int row = bm + (tid >> 2);
        int col = bn + (tid & 3) * 16;
        int idx = remain[row - LE];
        idx = min(max(idx, 0), LA - 1);
        const float* src = x_agent + (size_t)idx * CDIM + col;
        float* dq = qbuf + (size_t)row * CDIM + col;
        u16* db = qbuf_b + (size_t)row * CDIM + col;
#pragma unroll
        for (int i = 0; i < 4; ++i) {
            float4 v = *(const float4*)(src + i * 4);
            *(float4*)(dq + i * 4) = v;
            *(uint2*)(db + i * 4) = make_uint2(pk_bf16(v.x, v.y), pk_bf16(v.z, v.w));
        }
        return;
    }
    const int w = tid >> 6, lane = tid & 63;
    const int quad = lane >> 4, qi = lane & 15;
    const int wm = w >> 1, wn = w & 1;
    const u16* pa0 = h2_b + (size_t)(bm + wm * 32 + qi) * 256 + quad * 8;
    const u16* pa1 = pa0 + (size_t)16 * 256;
    const u16* pb0 = Wf3_b + (size_t)(bn + wn * 32 + qi) * 256 + quad * 8;
    const u16* pb1 = pb0 + (size_t)16 * 256;
    f32x4 a00 = {0, 0, 0, 0}, a01 = {0, 0, 0, 0}, a10 = {0, 0, 0, 0}, a11 = {0, 0, 0, 0};
#pragma unroll 4
    for (int k = 0; k < 256; k += 32) {
        bf16x8 x0 = *(const bf16x8*)(pa0 + k);
        bf16x8 x1 = *(const bf16x8*)(pa1 + k);
        bf16x8 y0 = *(const bf16x8*)(pb0 + k);
        bf16x8 y1 = *(const bf16x8*)(pb1 + k);
        a00 = __builtin_amdgcn_mfma_f32_16x16x32_bf16(x0, y0, a00, 0, 0, 0);
        a01 = __builtin_amdgcn_mfma_f32_16x16x32_bf16(x0, y1, a01, 0, 0, 0);
        a10 = __builtin_amdgcn_mfma_f32_16x16x32_bf16(x1, y0, a10, 0, 0, 0);
        a11 = __builtin_amdgcn_mfma_f32_16x16x32_bf16(x1, y1, a11, 0, 0, 0);
    }
#pragma unroll
    for (int i = 0; i < 2; ++i)
#pragma unroll
        for (int jj = 0; jj < 2; ++jj) {
            f32x4 acc = (i == 0) ? (jj == 0 ? a00 : a01) : (jj == 0 ? a10 : a11);
            int n = bn + wn * 32 + jj * 16 + qi;
            int mb = bm + wm * 32 + i * 16 + quad * 4;
            float bs = bf3[n];
#pragma unroll
            for (int r = 0; r < 4; ++r) {
                int row = mb + r;
                float v = acc[r] + bs;
                if (!matched[row]) v = x_ego[(size_t)row * CDIM + n];
                qbuf[(size_t)row * CDIM + n] = v;
                qbuf_b[(size_t)row * CDIM + n] = bf16_1(v);
            }
        }
}

// --------------------------- fused QKV projection (one dispatch) -----------
__global__ __launch_bounds__(256) void k_qkv(const u16* __restrict__ qbuf_b,
                                             const u16* __restrict__ kv_b,
                                             const u16* __restrict__ Wq,
                                             const u16* __restrict__ Wkv,
                                             const float* __restrict__ bqkv,
                                             u16* __restrict__ qb,
                                             u16* __restrict__ kbp,
                                             u16* __restrict__ vtb,
                                             float qscale) {
    int b = blockIdx.x;
    const u16 *A, *B;
    const float* bias;
    int bm, bn, mode;
    if (b < 192) {
        A = qbuf_b; B = Wq; bias = bqkv;
        bm = (b >> 2) * 64; bn = (b & 3) * 64; mode = 0;
    } else {
        int c = b - 192;
        A = kv_b; B = Wkv; bias = bqkv + 256;
        bm = (c >> 3) * 64; bn = (c & 7) * 64; mode = 1;
    }
    const int tid = threadIdx.x;
    const int w = tid >> 6, lane = tid & 63;
    const int quad = lane >> 4, qi = lane & 15;
    const int wm = w >> 1, wn = w & 1;
    const int K = 256;

    const u16* pa0 = A + (size_t)(bm + wm * 32 + qi) * K + quad * 8;
    const u16* pa1 = pa0 + (size_t)16 * K;
    const u16* pb0 = B + (size_t)(bn + wn * 32 + qi) * K + quad * 8;
    const u16* pb1 = pb0 + (size_t)16 * K;

    f32x4 acc00 = {0.f, 0.f, 0.f, 0.f}, acc01 = {0.f, 0.f, 0.f, 0.f};
    f32x4 acc10 = {0.f, 0.f, 0.f, 0.f}, acc11 = {0.f, 0.f, 0.f, 0.f};
#pragma unroll 4
    for (int k = 0; k < 256; k += 32) {
        bf16x8 a0 = *(const bf16x8*)(pa0 + k);
        bf16x8 a1 = *(const bf16x8*)(pa1 + k);
        bf16x8 b0 = *(const bf16x8*)(pb0 + k);
        bf16x8 b1 = *(const bf16x8*)(pb1 + k);
        acc00 = __builtin_amdgcn_mfma_f32_16x16x32_bf16(a0, b0, acc00, 0, 0, 0);
        acc01 = __builtin_amdgcn_mfma_f32_16x16x32_bf16(a0, b1, acc01, 0, 0, 0);
        acc10 = __builtin_amdgcn_mfma_f32_16x16x32_bf16(a1, b0, acc10, 0, 0, 0);
        acc11 = __builtin_amdgcn_mfma_f32_16x16x32_bf16(a1, b1, acc11, 0, 0, 0);
    }
#pragma unroll
    for (int i = 0; i < 2; ++i) {
#pragma unroll
        for (int j = 0; j < 2; ++j) {
            f32x4 acc = (i == 0) ? (j == 0 ? acc00 : acc01) : (j == 0 ? acc10 : acc11);
            int n = bn + wn * 32 + j * 16 + qi;
            int mbase = bm + wm * 32 + i * 16 + quad * 4;
            float bs = bias[n];
            float v[4];
#pragma unroll
            for (int r = 0; r < 4; ++r) v[r] = acc[r] + bs;
            if (mode == 0) {
#pragma unroll
                for (int r = 0; r < 4; ++r)
                    qb[(size_t)(mbase + r) * 256 + n] = bf16_1(v[r] * qscale);
            } else if (n < 256) {
#pragma unroll
                for (int r = 0; r < 4; ++r)
                    kbp[(size_t)(mbase + r) * 256 + n] = bf16_1(v[r]);
            } else {
                ushort4 o4;
                o4.x = bf16_1(v[0]); o4.y = bf16_1(v[1]);
                o4.z = bf16_1(v[2]); o4.w = bf16_1(v[3]);
                *(ushort4*)(vtb + (size_t)(n - 256) * LKC + mbase) = o4;
            }
        }
    }
}

// --------------------------- MFMA attention, LDS-staged K/V tiles ----------
__global__ __launch_bounds__(256) void attn_mfma(const u16* __restrict__ qb,
                                                 const u16* __restrict__ kb,
                                                 const u16* __restrict__ vtb,
                                                 float* __restrict__ Pl,
                                                 float* __restrict__ Pacc) {
    __shared__ u16 Kt[2][64 * 32];
    __shared__ u16 Vt[2][32 * 64];
    __shared__ u16 plds[4][16 * 64];
    const int tid = threadIdx.x;
    const int w = tid >> 6, lane = tid & 63;
    const int quad = lane >> 4, qi = lane & 15;
    const int h = blockIdx.y, ks = blockIdx.z;
    const int q0 = blockIdx.x * 64 + w * 16;

    bf16x8 qf = *(const bf16x8*)(qb + (size_t)(q0 + qi) * CDIM + h * DH + quad * 8);

    f32x4 O0 = {0.f, 0.f, 0.f, 0.f}, O1 = {0.f, 0.f, 0.f, 0.f};
    float lsum = 0.f;

    const int krow = w * 16 + (lane >> 2), kcp = lane & 3;
    const int kc = kcp ^ (krow & 3);
    const u16* kg0 = kb + (size_t)krow * CDIM + h * DH + kc * 8;
    const int kdst = krow * 32 + kcp * 8;
    const int vd = w * 8 + (lane >> 3), vcp = lane & 7;
    const int vc = vcp ^ (vd & 7);
    const u16* vg0 = vtb + (size_t)(h * DH + vd) * LKC + vc * 8;
    const int vdst = vd * 64 + vcp * 8;

    const int ka0 = qi * 32 + ((quad ^ (qi & 3)) << 3);
    const int v00o = qi * 64 + ((quad ^ (qi & 7)) << 3);
    const int v01o = qi * 64 + (((quad + 4) ^ (qi & 7)) << 3);
    const int swz = (qi & 7);
    const int rd0 = qi * 64 + ((quad ^ swz) << 3);
    const int rd1 = qi * 64 + (((4 + quad) ^ swz) << 3);
    const int half = (quad & 1) << 2;

    int kt = ks * (LKC / KSPLIT);
    {
        bf16x8 kr = *(const bf16x8*)(kg0 + (size_t)kt * CDIM);
        bf16x8 vr = *(const bf16x8*)(vg0 + kt);
        *(bf16x8*)&Kt[0][kdst] = kr;
        *(bf16x8*)&Vt[0][vdst] = vr;
    }
    int buf = 0;
    for (int it = 0; it < NIT; ++it, kt += 64) {
        __syncthreads();
        bf16x8 knext, vnext;
        const bool more = (it + 1 < NIT);
        if (more) {
            knext = *(const bf16x8*)(kg0 + (size_t)(kt + 64) * CDIM);
            vnext = *(const bf16x8*)(vg0 + kt + 64);
        }

        bf16x8 a0 = *(const bf16x8*)&Kt[buf][ka0];
        bf16x8 a1 = *(const bf16x8*)&Kt[buf][ka0 + 16 * 32];
        bf16x8 a2 = *(const bf16x8*)&Kt[buf][ka0 + 32 * 32];
        bf16x8 a3 = *(const bf16x8*)&Kt[buf][ka0 + 48 * 32];
        f32x4 z = {0.f, 0.f, 0.f, 0.f};
        f32x4 s0 = __builtin_amdgcn_mfma_f32_16x16x32_bf16(a0, qf, z, 0, 0, 0);
        f32x4 s1 = __builtin_amdgcn_mfma_f32_16x16x32_bf16(a1, qf, z, 0, 0, 0);
        f32x4 s2 = __builtin_amdgcn_mfma_f32_16x16x32_bf16(a2, qf, z, 0, 0, 0);
        f32x4 s3 = __builtin_amdgcn_mfma_f32_16x16x32_bf16(a3, qf, z, 0, 0, 0);

        float p0[4], p1[4], p2[4], p3[4];
#pragma unroll
        for (int r = 0; r < 4; ++r) {
            p0[r] = fast_exp2(s0[r]); p1[r] = fast_exp2(s1[r]);
            p2[r] = fast_exp2(s2[r]); p3[r] = fast_exp2(s3[r]);
            lsum += p0[r] + p1[r] + p2[r] + p3[r];
        }

        u16* pb = &plds[w][0];
#pragma unroll
        for (int t2 = 0; t2 < 4; ++t2) {
            int jg = t2 * 2 + (quad >> 1);
            int off = qi * 64 + ((jg ^ swz) << 3) + half;
            uint2 pw;
            float* pp = (t2 == 0) ? p0 : (t2 == 1) ? p1 : (t2 == 2) ? p2 : p3;
            pw.x = pk_bf16(pp[0], pp[1]);
            pw.y = pk_bf16(pp[2], pp[3]);
            *(uint2*)&pb[off] = pw;
        }
        bf16x8 pa0 = *(bf16x8*)&pb[rd0];
        bf16x8 pa1 = *(bf16x8*)&pb[rd1];

        bf16x8 v00 = *(const bf16x8*)&Vt[buf][v00o];
        bf16x8 v01 = *(const bf16x8*)&Vt[buf][v01o];
        bf16x8 v10 = *(const bf16x8*)&Vt[buf][v00o + 16 * 64];
        bf16x8 v11 = *(const bf16x8*)&Vt[buf][v01o + 16 * 64];
        O0 = __builtin_amdgcn_mfma_f32_16x16x32_bf16(pa0, v00, O0, 0, 0, 0);
        O0 = __builtin_amdgcn_mfma_f32_16x16x32_bf16(pa1, v01, O0, 0, 0, 0);
        O1 = __builtin_amdgcn_mfma_f32_16x16x32_bf16(pa0, v10, O1, 0, 0, 0);
        O1 = __builtin_amdgcn_mfma_f32_16x16x32_bf16(pa1, v11, O1, 0, 0, 0);

        if (more) {
            *(bf16x8*)&Kt[buf ^ 1][kdst] = knext;
            *(bf16x8*)&Vt[buf ^ 1][vdst] = vnext;
        }
        buf ^= 1;
    }

    lsum += __shfl_xor(lsum, 16, 64);
    lsum += __shfl_xor(lsum, 32, 64);

    int pbase = (h * KSPLIT + ks) * LQC + q0;
    if (quad == 0) Pl[pbase + qi] = lsum;
#pragma unroll
    for (int r = 0; r < 4; ++r) {
        int q = quad * 4 + r;
        float* pa = Pacc + (size_t)(pbase + q) * 32;
        pa[qi] = O0[r];
        pa[16 + qi] = O1[r];
    }
}

__global__ __launch_bounds__(256) void attn_combine(const float* __restrict__ Pl,
                                                    const float* __restrict__ Pacc,
                                                    u16* __restrict__ attn_b) {
    int t = blockIdx.x * 256 + threadIdx.x;  // LQC*64
    int row = t >> 6;
    int h = (t >> 3) & 7;
    int d4 = t & 7;
    float L = 0.f;
    float o[4] = {};
#pragma unroll
    for (int ck = 0; ck < KSPLIT; ++ck) {
        size_t pidx = (size_t)(h * KSPLIT + ck) * LQC + row;
        L += Pl[pidx];
        float4 a = *(const float4*)(Pacc + pidx * 32 + d4 * 4);
        o[0] += a.x; o[1] += a.y; o[2] += a.z; o[3] += a.w;
    }
    float inv = 1.0f / L;
    ushort4 ov;
    ov.x = bf16_1(o[0] * inv); ov.y = bf16_1(o[1] * inv);
    ov.z = bf16_1(o[2] * inv); ov.w = bf16_1(o[3] * inv);
    *(ushort4*)(attn_b + (size_t)row * CDIM + h * DH + d4 * 4) = ov;
}

// -------------------------------------------------------------- layernorm --
template <bool EMIT_BF16>
__global__ __launch_bounds__(256) void ln_kernel(const float* __restrict__ X,
                                                 const float* __restrict__ R,
                                                 const float* __restrict__ g,
                                                 const float* __restrict__ b,
                                                 float* __restrict__ out,
                                                 u16* __restrict__ out_b) {
    int lane = threadIdx.x & 63;
    int row = blockIdx.x * 4 + (threadIdx.x >> 6);
    const float* x = X + (size_t)row * CDIM;
    const float* r = R + (size_t)row * CDIM;
    float4 xv = *(const float4*)(x + lane * 4);
    float4 rv = *(const float4*)(r + lane * 4);
    float v[4] = {xv.x + rv.x, xv.y + rv.y, xv.z + rv.z, xv.w + rv.w};
    float s = v[0] + v[1] + v[2] + v[3];
    float sq = v[0] * v[0] + v[1] * v[1] + v[2] * v[2] + v[3] * v[3];
#pragma unroll
    for (int off = 32; off >= 1; off >>= 1) {
        s += __shfl_xor(s, off, 64);
        sq += __shfl_xor(sq, off, 64);
    }
    float mean = s * (1.f / 256.f);
    float var = sq * (1.f / 256.f) - mean * mean;
    float rstd = rsqrtf(var + 1e-5f);
    float4 gv = *(const float4*)(g + lane * 4);
    float4 bv = *(const float4*)(b + lane * 4);
    float4 o = make_float4((v[0] - mean) * rstd * gv.x + bv.x,
                           (v[1] - mean) * rstd * gv.y + bv.y,
                           (v[2] - mean) * rstd * gv.z + bv.z,
                           (v[3] - mean) * rstd * gv.w + bv.w);
    *(float4*)(out + (size_t)row * CDIM + lane * 4) = o;
    if (EMIT_BF16) {
        uint2 ob;
        ob.x = pk_bf16(o.x, o.y);
        ob.y = pk_bf16(o.z, o.w);
        *(uint2*)(out_b + (size_t)row * CDIM + lane * 4) = ob;
    }
}

// ------------------------------------------------------------------ launch --
extern "C" void kernel_launch(void* const* d_in, const int* in_sizes, int n_in,
                              void* d_out, int out_size, void* d_ws, size_t ws_size,
                              hipStream_t stream) {
    const float* x_ego = (const float*)d_in[0];
    const float* x_agent = (const float*)d_in[1];
    const float* Wf1 = (const float*)d_in[2];
    const float* bf1 = (const float*)d_in[3];
    const float* Wf2 = (const float*)d_in[4];
    const float* bf2 = (const float*)d_in[5];
    const float* Wf3 = (const float*)d_in[6];
    const float* bf3 = (const float*)d_in[7];
    const float* Wqkv = (const float*)d_in[8];
    const float* bqkv = (const float*)d_in[9];
    const float* Wo = (const float*)d_in[10];
    const float* bo = (const float*)d_in[11];
    const float* W1 = (const float*)d_in[12];
    const float* b1 = (const float*)d_in[13];
    const float* W2 = (const float*)d_in[14];
    const float* b2 = (const float*)d_in[15];
    const float* g1 = (const float*)d_in[16];
    const float* be1 = (const float*)d_in[17];
    const float* g2 = (const float*)d_in[18];
    const float* be2 = (const float*)d_in[19];
    const int* pos_ego = (const int*)d_in[20];
    const int* pos_agent = (const int*)d_in[21];

    float* ws = (float*)d_ws;
    size_t o = 0;
    float* qbuf = ws + o; o += 786432;
    float* o2 = ws + o; o += 786432;
    float* yq = ws + o; o += 786432;
    float* ff2 = o2;  // o2 consumed by ln1 before ffn2 writes ff2
    float* Pl = ws + o; o += HN * KSPLIT * LQC;                 // 196608
    float* Pacc = ws + o; o += (size_t)HN * KSPLIT * LQC * 32;  // 6291456
    u16* wb = (u16*)(ws + o); o += 524288;        // 1,048,576 u16
    u16* fused_b = (u16*)(ws + o); o += 524288;   // LE*512
    u16* h1_b = (u16*)(ws + o); o += 262144;      // LE*256
    u16* h2_b = (u16*)(ws + o); o += 262144;
    u16* qbuf_b = (u16*)(ws + o); o += 393216;    // LQC*256
    u16* kv_b = (u16*)(ws + o); o += 524288;      // LKC*256
    u16* qb = (u16*)(ws + o); o += 393216;
    u16* kb = (u16*)(ws + o); o += 524288;
    u16* vtb = (u16*)(ws + o); o += 524288;
    u16* attn_b = (u16*)(ws + o); o += 393216;
    u16* ff1_b = (u16*)(ws + o); o += 1572864;    // LQC*1024
    u16* yq_b = (u16*)(ws + o); o += 393216;
    int* afe = (int*)(ws + o);
    int* matched = afe + LE;
    int* unmatched = matched + LE;
    int* remain = unmatched + LA;

    const u16* Wf1_b = wb + 0;
    const u16* Wf2_b = wb + 131072;
    const u16* Wf3_b = wb + 196608;
    const u16* Wq_b = wb + 262144;
    const u16* Wkv_b = wb + 327680;
    const u16* Wo_b = wb + 458752;
    const u16* W1_b = wb + 524288;
    const u16* W2_b = wb + 786432;

    // 1. matching (LDS hash join)
    k_match<<<1, 1024, 0, stream>>>(pos_ego, pos_agent, afe, matched, unmatched);
    WPtrs wp;
    wp.p[0] = Wf1; wp.p[1] = Wf2; wp.p[2] = Wf3; wp.p[3] = Wqkv;
    wp.p[4] = Wo; wp.p[5] = W1; wp.p[6] = W2;
    // 2. stage2: scan + build_fused + weight cvt + kv staging
    k_stage2<<<1537, 256, 0, stream>>>(unmatched, remain, afe, x_ego, x_agent,
                                       fused_b, wp, wb, kv_b);

    const float qscale = 0.17677669529663687f * 1.4426950408889634f;

    // 3-5. fusion MLP (finalize folded into MLP3)
    gemm_bf16<1, true><<<dim3(4, 32), 256, 0, stream>>>(fused_b, Wf1_b, bf1, h1_b,
                                                        LE, 256, 512);
    gemm_bf16<1, true><<<dim3(4, 32), 256, 0, stream>>>(h1_b, Wf2_b, bf2, h2_b,
                                                        LE, 256, 256);
    k_mlp3f<<<dim3(4, 48), 256, 0, stream>>>(h2_b, Wf3_b, bf3, matched, remain,
                                             x_ego, x_agent, qbuf, qbuf_b);

    // 6. fused QKV projections
    k_qkv<<<704, 256, 0, stream>>>(qbuf_b, kv_b, Wq_b, Wkv_b, bqkv, qb, kb, vtb, qscale);

    // 7. attention (KSPLIT=8)
    attn_mfma<<<dim3(LQC / 64, HN, KSPLIT), 256, 0, stream>>>(qb, kb, vtb, Pl, Pacc);
    // 8. combine
    attn_combine<<<(LQC * 64) / 256, 256, 0, stream>>>(Pl, Pacc, attn_b);

    // 9-10. out-proj + LN1
    gemm_bf16<0, false><<<dim3(4, 48), 256, 0, stream>>>(attn_b, Wo_b, bo, o2,
                                                         LQC, 256, 256);
    ln_kernel<true><<<LQC / 4, 256, 0, stream>>>(qbuf, o2, g1, be1, yq, yq_b);

    // 11-13. FFN + LN2
    gemm_bf16<1, true><<<dim3(16, 48), 256, 0, stream>>>(yq_b, W1_b, b1, ff1_b,
                                                         LQC, DFF, 256);
    gemm_bf16<0, false><<<dim3(4, 48), 256, 0, stream>>>(ff1_b, W2_b, b2, ff2,
                                                         LQC, 256, DFF);
    ln_kernel<false><<<LQC / 4, 256, 0, stream>>>(yq, ff2, g2, be2, (float*)d_out, nullptr);
}